// Round 5
// baseline (834.509 us; speedup 1.0000x reference)
//
#include <hip/hip_runtime.h>
#include <hip/hip_bf16.h>

#define HID 64
#define IN_EMB 128
#define IN_DIM 130
#define ROWS_PER_BKT 128
#define LOG_RPB 7
#define MAX_BKT 1024          // 100000/128 = 782 buckets actually used
#define PART_CHUNK 16384      // edges per partition block
#define NPB 32                // nodes per block in dense layers

typedef __hip_bfloat16 bf16;

// ---------------- coarse histogram over row-buckets --------------------------
__global__ __launch_bounds__(256) void bhist_kernel(const int* __restrict__ row,
                                                    int* __restrict__ bcnt,
                                                    int nE, int nbkt) {
  __shared__ int h[MAX_BKT];
  for (int i = threadIdx.x; i < nbkt; i += 256) h[i] = 0;
  __syncthreads();
  const int stride = gridDim.x * 256;
  for (int e = blockIdx.x * 256 + threadIdx.x; e < nE; e += stride)
    atomicAdd(&h[row[e] >> LOG_RPB], 1);
  __syncthreads();
  for (int i = threadIdx.x; i < nbkt; i += 256)
    if (h[i]) atomicAdd(&bcnt[i], h[i]);
}

// ---------------- exclusive scan of bucket counts (1 block) ------------------
__global__ __launch_bounds__(1024) void bscan_kernel(const int* __restrict__ bcnt,
                                                     int* __restrict__ bstart,
                                                     int* __restrict__ bcur,
                                                     int* __restrict__ row_ptr,
                                                     int n, int nbkt) {
  __shared__ int s[1024];
  const int t = threadIdx.x;
  const int v = (t < nbkt) ? bcnt[t] : 0;
  s[t] = v;
  __syncthreads();
  for (int off = 1; off < 1024; off <<= 1) {
    int u = (t >= off) ? s[t - off] : 0;
    __syncthreads();
    s[t] += u;
    __syncthreads();
  }
  if (t < nbkt) { int ex = s[t] - v; bstart[t] = ex; bcur[t] = ex; }
  if (t == 0) { bstart[nbkt] = s[1023]; row_ptr[n] = s[1023]; }   // == nE
}

// ---------------- partition edges into row-buckets (coalesced runs) ----------
// packed edge: .x = col | (local_row << 20), .y = bits(val)
__global__ __launch_bounds__(256) void partition_kernel(
    const int* __restrict__ row, const int* __restrict__ col,
    const float* __restrict__ vals, int* __restrict__ bcur,
    int2* __restrict__ tmp, int nE) {
  __shared__ int h[MAX_BKT];
  __shared__ int cur[MAX_BKT];
  const int t = threadIdx.x;
  const int base = blockIdx.x * PART_CHUNK;
  for (int i = t; i < MAX_BKT; i += 256) h[i] = 0;
  __syncthreads();
  for (int k = 0; k < PART_CHUNK / 256; ++k) {
    int e = base + k * 256 + t;
    if (e < nE) atomicAdd(&h[row[e] >> LOG_RPB], 1);
  }
  __syncthreads();
  for (int b = t; b < MAX_BKT; b += 256)
    if (h[b] > 0) cur[b] = atomicAdd(&bcur[b], h[b]);
  __syncthreads();
  for (int k = 0; k < PART_CHUNK / 256; ++k) {
    int e = base + k * 256 + t;
    if (e < nE) {
      int r = row[e];
      int b = r >> LOG_RPB;
      int p = atomicAdd(&cur[b], 1);
      tmp[p] = make_int2(col[e] | ((r & (ROWS_PER_BKT - 1)) << 20),
                         __float_as_int(vals[e]));
    }
  }
}

// ---------------- per-bucket counting sort -> exact CSR + row_ptr ------------
__global__ __launch_bounds__(256) void bucket_sort_kernel(
    const int* __restrict__ bstart, const int2* __restrict__ tmp,
    int2* __restrict__ ce, int* __restrict__ row_ptr, int n) {
  __shared__ int rcnt[ROWS_PER_BKT];
  __shared__ int rpos[ROWS_PER_BKT];
  __shared__ int sc[ROWS_PER_BKT];
  const int t = threadIdx.x;
  const int b = blockIdx.x;
  const int start = bstart[b];
  const int end   = bstart[b + 1];
  if (t < ROWS_PER_BKT) rcnt[t] = 0;
  __syncthreads();
  for (int i = start + t; i < end; i += 256)
    atomicAdd(&rcnt[tmp[i].x >> 20], 1);
  __syncthreads();
  if (t < ROWS_PER_BKT) sc[t] = rcnt[t];
  __syncthreads();
  for (int off = 1; off < ROWS_PER_BKT; off <<= 1) {
    int u = (t < ROWS_PER_BKT && t >= off) ? sc[t - off] : 0;
    __syncthreads();
    if (t < ROWS_PER_BKT) sc[t] += u;
    __syncthreads();
  }
  if (t < ROWS_PER_BKT) {
    int ex = sc[t] - rcnt[t];
    int gpos = start + ex;
    rpos[t] = gpos;
    int gr = b * ROWS_PER_BKT + t;
    if (gr < n) row_ptr[gr] = gpos;
  }
  __syncthreads();
  for (int i = start + t; i < end; i += 256) {
    int2 e = tmp[i];
    int p = atomicAdd(&rpos[e.x >> 20], 1);
    ce[p] = make_int2(e.x & 0xFFFFF, e.y);
  }
}

// ---------------- Linear1: LDS-staged, k-packed W, VALU-bound ----------------
// sW4 layout: [k4][f][c] so lane f reads its weight chunk as aligned b128 with
// even bank spread; sE rows broadcast-read (wave-uniform addr -> conflict-free).
__global__ __launch_bounds__(256) void lin1_kernel(
    const float* __restrict__ emb, const float* __restrict__ deg,
    const float* __restrict__ seed, const float* __restrict__ W1,
    const float* __restrict__ b1, bf16* __restrict__ out, int n) {
  __shared__ float sW4[(IN_EMB / 4) * HID * 4];   // 32 KB, k=0..127
  __shared__ float sWt[2 * HID];                  // k=128,129
  __shared__ float sE[NPB * 132];                 // 16.9 KB (132: 16B-aligned rows)
  const int t = threadIdx.x;
  for (int i = t; i < IN_DIM * HID; i += 256) {
    int k = i >> 6, f = i & 63;
    if (k < IN_EMB) sW4[((k >> 2) * HID + f) * 4 + (k & 3)] = W1[i];
    else sWt[(k - IN_EMB) * HID + f] = W1[i];
  }
  const int base = blockIdx.x * NPB;
  if (base + NPB <= n) {
    const float4* ev = (const float4*)(emb + (size_t)base * IN_EMB);
    for (int i = t; i < NPB * (IN_EMB / 4); i += 256) {   // 1024 float4, coalesced
      int nn = i >> 5, k4 = i & 31;
      *(float4*)&sE[nn * 132 + 4 * k4] = ev[i];
    }
    if (t < NPB) sE[t * 132 + 128] = deg[base + t];
    else if (t < 2 * NPB) { int nn = t - NPB; sE[nn * 132 + 129] = seed[base + nn]; }
  } else {
    for (int i = t; i < NPB * IN_EMB; i += 256) {
      int nn = i >> 7, k = i & 127;
      int node = base + nn;
      sE[nn * 132 + k] = (node < n) ? emb[(size_t)node * IN_EMB + k] : 0.f;
    }
    if (t < NPB) { int node = base + t; sE[t * 132 + 128] = (node < n) ? deg[node] : 0.f; }
    else if (t < 2 * NPB) { int nn = t - NPB; int node = base + nn;
      sE[nn * 132 + 129] = (node < n) ? seed[node] : 0.f; }
  }
  __syncthreads();

  const int lane = t & 63, g = t >> 6;
  float a[8] = {};
#pragma unroll 4
  for (int k4 = 0; k4 < IN_EMB / 4; ++k4) {
    const float4 w = *(const float4*)&sW4[(k4 * HID + lane) * 4];
#pragma unroll
    for (int j = 0; j < 8; ++j) {
      const float4 e = *(const float4*)&sE[(g * 8 + j) * 132 + 4 * k4];
      a[j] += e.x * w.x + e.y * w.y + e.z * w.z + e.w * w.w;
    }
  }
  const float w128 = sWt[lane], w129 = sWt[HID + lane];
  const float bias = b1[lane];
#pragma unroll
  for (int j = 0; j < 8; ++j) {
    const int nn = g * 8 + j;
    const int node = base + nn;
    if (node >= n) break;
    float r = a[j] + sE[nn * 132 + 128] * w128 + sE[nn * 132 + 129] * w129 + bias;
    out[(size_t)node * HID + lane] = __float2bfloat16(r);
  }
}

// ---------------- SpMM1 (exact CSR, gather-only, bf16) + fused ReLU ----------
__global__ __launch_bounds__(256) void spmm_csr_kernel(
    const int* __restrict__ row_ptr, const int2* __restrict__ ce,
    const bf16* __restrict__ x, bf16* __restrict__ y, int n) {
  const int lane = threadIdx.x & 63;
  const int r = blockIdx.x * 4 + (threadIdx.x >> 6);
  if (r >= n) return;
  int i = row_ptr[r];
  const int end = row_ptr[r + 1];
  float acc = 0.f;
  for (; i + 8 <= end; i += 8) {
    int2 e0 = ce[i],   e1 = ce[i+1], e2 = ce[i+2], e3 = ce[i+3];
    int2 e4 = ce[i+4], e5 = ce[i+5], e6 = ce[i+6], e7 = ce[i+7];
    float g0 = __bfloat162float(x[(size_t)e0.x * HID + lane]);
    float g1 = __bfloat162float(x[(size_t)e1.x * HID + lane]);
    float g2 = __bfloat162float(x[(size_t)e2.x * HID + lane]);
    float g3 = __bfloat162float(x[(size_t)e3.x * HID + lane]);
    float g4 = __bfloat162float(x[(size_t)e4.x * HID + lane]);
    float g5 = __bfloat162float(x[(size_t)e5.x * HID + lane]);
    float g6 = __bfloat162float(x[(size_t)e6.x * HID + lane]);
    float g7 = __bfloat162float(x[(size_t)e7.x * HID + lane]);
    acc += __int_as_float(e0.y) * g0 + __int_as_float(e1.y) * g1
         + __int_as_float(e2.y) * g2 + __int_as_float(e3.y) * g3
         + __int_as_float(e4.y) * g4 + __int_as_float(e5.y) * g5
         + __int_as_float(e6.y) * g6 + __int_as_float(e7.y) * g7;
  }
  for (; i < end; ++i) {
    int2 e0 = ce[i];
    acc += __int_as_float(e0.y) * __bfloat162float(x[(size_t)e0.x * HID + lane]);
  }
  y[(size_t)r * HID + lane] = __float2bfloat16(fmaxf(acc, 0.f));
}

// ---------------- Linear2: LDS-staged like lin1 ------------------------------
__global__ __launch_bounds__(256) void lin2_kernel(
    const bf16* __restrict__ yin, const float* __restrict__ W2,
    const float* __restrict__ b2, bf16* __restrict__ xout, int n) {
  __shared__ float sW4[(HID / 4) * HID * 4];   // 16 KB
  __shared__ float sE[NPB * 68];               // 8.7 KB
  const int t = threadIdx.x;
  for (int i = t; i < HID * HID; i += 256) {
    int k = i >> 6, f = i & 63;
    sW4[((k >> 2) * HID + f) * 4 + (k & 3)] = W2[i];
  }
  const int base = blockIdx.x * NPB;
  if (base + NPB <= n) {
    const ushort4* yv = (const ushort4*)(yin + (size_t)base * HID);
    for (int i = t; i < NPB * (HID / 4); i += 256) {   // 512 x 8B, coalesced
      int nn = i >> 4, k4 = i & 15;
      ushort4 u = yv[i];
      float4 v;
      v.x = __uint_as_float((unsigned)u.x << 16);
      v.y = __uint_as_float((unsigned)u.y << 16);
      v.z = __uint_as_float((unsigned)u.z << 16);
      v.w = __uint_as_float((unsigned)u.w << 16);
      *(float4*)&sE[nn * 68 + 4 * k4] = v;
    }
  } else {
    for (int i = t; i < NPB * HID; i += 256) {
      int nn = i >> 6, k = i & 63;
      int node = base + nn;
      sE[nn * 68 + k] = (node < n) ? __bfloat162float(yin[(size_t)node * HID + k]) : 0.f;
    }
  }
  __syncthreads();

  const int lane = t & 63, g = t >> 6;
  float a[8] = {};
#pragma unroll 4
  for (int k4 = 0; k4 < HID / 4; ++k4) {
    const float4 w = *(const float4*)&sW4[(k4 * HID + lane) * 4];
#pragma unroll
    for (int j = 0; j < 8; ++j) {
      const float4 e = *(const float4*)&sE[(g * 8 + j) * 68 + 4 * k4];
      a[j] += e.x * w.x + e.y * w.y + e.z * w.z + e.w * w.w;
    }
  }
  const float bias = b2[lane];
#pragma unroll
  for (int j = 0; j < 8; ++j) {
    const int node = base + g * 8 + j;
    if (node >= n) break;
    xout[(size_t)node * HID + lane] = __float2bfloat16(a[j] + bias);
  }
}

// ---------------- SpMM2 + fused ReLU + Wout-dot + global reduce --------------
__global__ __launch_bounds__(256) void spmm2_fused_kernel(
    const int* __restrict__ row_ptr, const int2* __restrict__ ce,
    const bf16* __restrict__ x, const float* __restrict__ Wout,
    const float* __restrict__ bout, float* __restrict__ out, int n) {
  const int lane = threadIdx.x & 63;
  const int g = threadIdx.x >> 6;
  const int r = blockIdx.x * 4 + g;
  float wpart = 0.f;
  if (r < n) {
    int i = row_ptr[r];
    const int end = row_ptr[r + 1];
    float acc = 0.f;
    for (; i + 8 <= end; i += 8) {
      int2 e0 = ce[i],   e1 = ce[i+1], e2 = ce[i+2], e3 = ce[i+3];
      int2 e4 = ce[i+4], e5 = ce[i+5], e6 = ce[i+6], e7 = ce[i+7];
      float g0 = __bfloat162float(x[(size_t)e0.x * HID + lane]);
      float g1 = __bfloat162float(x[(size_t)e1.x * HID + lane]);
      float g2 = __bfloat162float(x[(size_t)e2.x * HID + lane]);
      float g3 = __bfloat162float(x[(size_t)e3.x * HID + lane]);
      float g4 = __bfloat162float(x[(size_t)e4.x * HID + lane]);
      float g5 = __bfloat162float(x[(size_t)e5.x * HID + lane]);
      float g6 = __bfloat162float(x[(size_t)e6.x * HID + lane]);
      float g7 = __bfloat162float(x[(size_t)e7.x * HID + lane]);
      acc += __int_as_float(e0.y) * g0 + __int_as_float(e1.y) * g1
           + __int_as_float(e2.y) * g2 + __int_as_float(e3.y) * g3
           + __int_as_float(e4.y) * g4 + __int_as_float(e5.y) * g5
           + __int_as_float(e6.y) * g6 + __int_as_float(e7.y) * g7;
    }
    for (; i < end; ++i) {
      int2 e0 = ce[i];
      acc += __int_as_float(e0.y) * __bfloat162float(x[(size_t)e0.x * HID + lane]);
    }
    wpart = fmaxf(acc, 0.f) * Wout[lane];
  }
  for (int off = 32; off; off >>= 1) wpart += __shfl_down(wpart, off, 64);
  __shared__ float part[4];
  if (lane == 0) part[g] = wpart;
  __syncthreads();
  if (threadIdx.x == 0) {
    float s = part[0] + part[1] + part[2] + part[3];
    if (blockIdx.x == 0) s += bout[0];
    atomicAdd(out, s);
  }
}

extern "C" void kernel_launch(void* const* d_in, const int* in_sizes, int n_in,
                              void* d_out, int out_size, void* d_ws, size_t ws_size,
                              hipStream_t stream) {
  const float* emb  = (const float*)d_in[0];
  const float* deg  = (const float*)d_in[1];
  const float* seed = (const float*)d_in[2];
  const int*   row  = (const int*)d_in[3];
  const int*   col  = (const int*)d_in[4];
  const float* vals = (const float*)d_in[5];
  const float* W1   = (const float*)d_in[6];
  const float* b1   = (const float*)d_in[7];
  const float* W2   = (const float*)d_in[8];
  const float* b2   = (const float*)d_in[9];
  const float* Wout = (const float*)d_in[10];
  const float* bout = (const float*)d_in[11];
  float* out = (float*)d_out;

  const int n  = in_sizes[0] / IN_EMB;   // 100000
  const int nE = in_sizes[3];            // 3200000
  const int nbkt = (n + ROWS_PER_BKT - 1) / ROWS_PER_BKT;   // 782

  // ---- workspace layout ----
  char* ws = (char*)d_ws;
  int2* ce   = (int2*)ws;  ws += (size_t)nE * sizeof(int2);             // live to end
  char* tmpb = ws;
  int2* tmp  = (int2*)ws;  ws += (size_t)nE * sizeof(int2);             // dead after sort
  bf16* xa   = (bf16*)ws;  ws += ((size_t)n * HID * 2 + 255) & ~255ULL;
  bf16* xb   = (bf16*)ws;  ws += ((size_t)n * HID * 2 + 255) & ~255ULL;
  int* row_ptr = (int*)ws; ws += ((size_t)(n + 1) * 4 + 255) & ~255ULL;
  int* bcnt    = (int*)ws; ws += ((size_t)nbkt * 4 + 255) & ~255ULL;
  int* bstart  = (int*)ws; ws += ((size_t)(nbkt + 1) * 4 + 255) & ~255ULL;
  int* bcur    = (int*)ws;
  bf16* ya = (bf16*)tmpb;   // alias: tmp dead before spmm1 writes ya

  const int node_blocks = (n + NPB - 1) / NPB;
  const int row_blocks  = (n + 3) / 4;
  const int part_blocks = (nE + PART_CHUNK - 1) / PART_CHUNK;

  // ---- CSR build ----
  hipMemsetAsync(bcnt, 0, (size_t)nbkt * sizeof(int), stream);
  bhist_kernel<<<512, 256, 0, stream>>>(row, bcnt, nE, nbkt);
  bscan_kernel<<<1, 1024, 0, stream>>>(bcnt, bstart, bcur, row_ptr, n, nbkt);
  partition_kernel<<<part_blocks, 256, 0, stream>>>(row, col, vals, bcur, tmp, nE);
  bucket_sort_kernel<<<nbkt, 256, 0, stream>>>(bstart, tmp, ce, row_ptr, n);

  // ---- network ----
  lin1_kernel<<<node_blocks, 256, 0, stream>>>(emb, deg, seed, W1, b1, xa, n);
  spmm_csr_kernel<<<row_blocks, 256, 0, stream>>>(row_ptr, ce, xa, ya, n);
  lin2_kernel<<<node_blocks, 256, 0, stream>>>(ya, W2, b2, xb, n);
  hipMemsetAsync(out, 0, sizeof(float), stream);
  spmm2_fused_kernel<<<row_blocks, 256, 0, stream>>>(row_ptr, ce, xb, Wout, bout, out, n);
}

// Round 6
// 593.185 us; speedup vs baseline: 1.4068x; 1.4068x over previous
//
#include <hip/hip_runtime.h>
#include <hip/hip_bf16.h>

#define HID 64
#define IN_EMB 128
#define IN_DIM 130
#define ROWS_PER_BKT 128
#define LOG_RPB 7
#define MAX_BKT 1024          // 100000/128 = 782 buckets actually used
#define PART_CHUNK 16384      // edges per partition block
#define NPB 32                // nodes per block in dense layers

typedef __hip_bfloat16 bf16;

__device__ __forceinline__ float bf2f(unsigned short u) {
  return __uint_as_float((unsigned)u << 16);
}

// ---------------- coarse histogram over row-buckets --------------------------
__global__ __launch_bounds__(256) void bhist_kernel(const int* __restrict__ row,
                                                    int* __restrict__ bcnt,
                                                    int nE, int nbkt) {
  __shared__ int h[MAX_BKT];
  for (int i = threadIdx.x; i < nbkt; i += 256) h[i] = 0;
  __syncthreads();
  const int stride = gridDim.x * 256;
  for (int e = blockIdx.x * 256 + threadIdx.x; e < nE; e += stride)
    atomicAdd(&h[row[e] >> LOG_RPB], 1);
  __syncthreads();
  for (int i = threadIdx.x; i < nbkt; i += 256)
    if (h[i]) atomicAdd(&bcnt[i], h[i]);
}

// ---------------- exclusive scan of bucket counts (1 block) ------------------
__global__ __launch_bounds__(1024) void bscan_kernel(const int* __restrict__ bcnt,
                                                     int* __restrict__ bstart,
                                                     int* __restrict__ bcur,
                                                     int* __restrict__ row_ptr,
                                                     int n, int nbkt) {
  __shared__ int s[1024];
  const int t = threadIdx.x;
  const int v = (t < nbkt) ? bcnt[t] : 0;
  s[t] = v;
  __syncthreads();
  for (int off = 1; off < 1024; off <<= 1) {
    int u = (t >= off) ? s[t - off] : 0;
    __syncthreads();
    s[t] += u;
    __syncthreads();
  }
  if (t < nbkt) { int ex = s[t] - v; bstart[t] = ex; bcur[t] = ex; }
  if (t == 0) { bstart[nbkt] = s[1023]; row_ptr[n] = s[1023]; }   // == nE
}

// ---------------- partition edges into row-buckets (coalesced runs) ----------
// packed edge: .x = col | (local_row << 20), .y = bits(val)
__global__ __launch_bounds__(256) void partition_kernel(
    const int* __restrict__ row, const int* __restrict__ col,
    const float* __restrict__ vals, int* __restrict__ bcur,
    int2* __restrict__ tmp, int nE) {
  __shared__ int h[MAX_BKT];
  __shared__ int cur[MAX_BKT];
  const int t = threadIdx.x;
  const int base = blockIdx.x * PART_CHUNK;
  for (int i = t; i < MAX_BKT; i += 256) h[i] = 0;
  __syncthreads();
  for (int k = 0; k < PART_CHUNK / 256; ++k) {
    int e = base + k * 256 + t;
    if (e < nE) atomicAdd(&h[row[e] >> LOG_RPB], 1);
  }
  __syncthreads();
  for (int b = t; b < MAX_BKT; b += 256)
    if (h[b] > 0) cur[b] = atomicAdd(&bcur[b], h[b]);
  __syncthreads();
  for (int k = 0; k < PART_CHUNK / 256; ++k) {
    int e = base + k * 256 + t;
    if (e < nE) {
      int r = row[e];
      int b = r >> LOG_RPB;
      int p = atomicAdd(&cur[b], 1);
      tmp[p] = make_int2(col[e] | ((r & (ROWS_PER_BKT - 1)) << 20),
                         __float_as_int(vals[e]));
    }
  }
}

// ---------------- per-bucket counting sort -> exact CSR + row_ptr ------------
__global__ __launch_bounds__(256) void bucket_sort_kernel(
    const int* __restrict__ bstart, const int2* __restrict__ tmp,
    int2* __restrict__ ce, int* __restrict__ row_ptr, int n) {
  __shared__ int rcnt[ROWS_PER_BKT];
  __shared__ int rpos[ROWS_PER_BKT];
  __shared__ int sc[ROWS_PER_BKT];
  const int t = threadIdx.x;
  const int b = blockIdx.x;
  const int start = bstart[b];
  const int end   = bstart[b + 1];
  if (t < ROWS_PER_BKT) rcnt[t] = 0;
  __syncthreads();
  for (int i = start + t; i < end; i += 256)
    atomicAdd(&rcnt[tmp[i].x >> 20], 1);
  __syncthreads();
  if (t < ROWS_PER_BKT) sc[t] = rcnt[t];
  __syncthreads();
  for (int off = 1; off < ROWS_PER_BKT; off <<= 1) {
    int u = (t < ROWS_PER_BKT && t >= off) ? sc[t - off] : 0;
    __syncthreads();
    if (t < ROWS_PER_BKT) sc[t] += u;
    __syncthreads();
  }
  if (t < ROWS_PER_BKT) {
    int ex = sc[t] - rcnt[t];
    int gpos = start + ex;
    rpos[t] = gpos;
    int gr = b * ROWS_PER_BKT + t;
    if (gr < n) row_ptr[gr] = gpos;
  }
  __syncthreads();
  for (int i = start + t; i < end; i += 256) {
    int2 e = tmp[i];
    int p = atomicAdd(&rpos[e.x >> 20], 1);
    ce[p] = make_int2(e.x & 0xFFFFF, e.y);
  }
}

// ---------------- Linear1: LDS-staged, k-packed W, VALU-bound ----------------
__global__ __launch_bounds__(256) void lin1_kernel(
    const float* __restrict__ emb, const float* __restrict__ deg,
    const float* __restrict__ seed, const float* __restrict__ W1,
    const float* __restrict__ b1, bf16* __restrict__ out, int n) {
  __shared__ float sW4[(IN_EMB / 4) * HID * 4];   // 32 KB, k=0..127
  __shared__ float sWt[2 * HID];                  // k=128,129
  __shared__ float sE[NPB * 132];                 // 16.9 KB
  const int t = threadIdx.x;
  for (int i = t; i < IN_DIM * HID; i += 256) {
    int k = i >> 6, f = i & 63;
    if (k < IN_EMB) sW4[((k >> 2) * HID + f) * 4 + (k & 3)] = W1[i];
    else sWt[(k - IN_EMB) * HID + f] = W1[i];
  }
  const int base = blockIdx.x * NPB;
  if (base + NPB <= n) {
    const float4* ev = (const float4*)(emb + (size_t)base * IN_EMB);
    for (int i = t; i < NPB * (IN_EMB / 4); i += 256) {
      int nn = i >> 5, k4 = i & 31;
      *(float4*)&sE[nn * 132 + 4 * k4] = ev[i];
    }
    if (t < NPB) sE[t * 132 + 128] = deg[base + t];
    else if (t < 2 * NPB) { int nn = t - NPB; sE[nn * 132 + 129] = seed[base + nn]; }
  } else {
    for (int i = t; i < NPB * IN_EMB; i += 256) {
      int nn = i >> 7, k = i & 127;
      int node = base + nn;
      sE[nn * 132 + k] = (node < n) ? emb[(size_t)node * IN_EMB + k] : 0.f;
    }
    if (t < NPB) { int node = base + t; sE[t * 132 + 128] = (node < n) ? deg[node] : 0.f; }
    else if (t < 2 * NPB) { int nn = t - NPB; int node = base + nn;
      sE[nn * 132 + 129] = (node < n) ? seed[node] : 0.f; }
  }
  __syncthreads();

  const int lane = t & 63, g = t >> 6;
  float a[8] = {};
#pragma unroll 4
  for (int k4 = 0; k4 < IN_EMB / 4; ++k4) {
    const float4 w = *(const float4*)&sW4[(k4 * HID + lane) * 4];
#pragma unroll
    for (int j = 0; j < 8; ++j) {
      const float4 e = *(const float4*)&sE[(g * 8 + j) * 132 + 4 * k4];
      a[j] += e.x * w.x + e.y * w.y + e.z * w.z + e.w * w.w;
    }
  }
  const float w128 = sWt[lane], w129 = sWt[HID + lane];
  const float bias = b1[lane];
#pragma unroll
  for (int j = 0; j < 8; ++j) {
    const int nn = g * 8 + j;
    const int node = base + nn;
    if (node >= n) break;
    float r = a[j] + sE[nn * 132 + 128] * w128 + sE[nn * 132 + 129] * w129 + bias;
    out[(size_t)node * HID + lane] = __float2bfloat16(r);
  }
}

// ---- pair-gather: lanes 0-31 take edge A, lanes 32-63 edge B; ushort2/lane --
#define PAIR(ea, eb)                                                          \
  {                                                                           \
    const int   c = half ? (eb).x : (ea).x;                                   \
    const float v = __int_as_float(half ? (eb).y : (ea).y);                   \
    const ushort2 u = *(const ushort2*)((const unsigned short*)x +            \
                                        ((size_t)c << 6) + (hl << 1));        \
    acc.x += v * bf2f(u.x);                                                   \
    acc.y += v * bf2f(u.y);                                                   \
  }

// ---------------- SpMM1 (exact CSR, pair-gather) + fused ReLU ----------------
__global__ __launch_bounds__(256) void spmm_csr_kernel(
    const int* __restrict__ row_ptr, const int2* __restrict__ ce,
    const bf16* __restrict__ x, bf16* __restrict__ y, int n) {
  const int lane = threadIdx.x & 63;
  const int half = lane >> 5;
  const int hl   = lane & 31;
  const int r = blockIdx.x * 4 + (threadIdx.x >> 6);
  if (r >= n) return;
  int i = row_ptr[r];
  const int end = row_ptr[r + 1];
  float2 acc = {0.f, 0.f};
  for (; i + 16 <= end; i += 16) {   // 8 independent pair-gathers in flight
    int2 e0 = ce[i],    e1 = ce[i+1],  e2 = ce[i+2],  e3 = ce[i+3];
    int2 e4 = ce[i+4],  e5 = ce[i+5],  e6 = ce[i+6],  e7 = ce[i+7];
    int2 e8 = ce[i+8],  e9 = ce[i+9],  ea = ce[i+10], eb = ce[i+11];
    int2 ec = ce[i+12], ed = ce[i+13], ee = ce[i+14], ef = ce[i+15];
    PAIR(e0, e1); PAIR(e2, e3); PAIR(e4, e5); PAIR(e6, e7);
    PAIR(e8, e9); PAIR(ea, eb); PAIR(ec, ed); PAIR(ee, ef);
  }
  for (; i + 2 <= end; i += 2) {
    int2 ea = ce[i], eb = ce[i + 1];
    PAIR(ea, eb);
  }
  if (i < end) {   // odd tail: high half duplicates gather with v=0
    int2 ea = ce[i];
    const int   c = ea.x;
    const float v = half ? 0.f : __int_as_float(ea.y);
    const ushort2 u = *(const ushort2*)((const unsigned short*)x +
                                        ((size_t)c << 6) + (hl << 1));
    acc.x += v * bf2f(u.x);
    acc.y += v * bf2f(u.y);
  }
  // combine halves: lane L gets full sum for features {2L, 2L+1}
  acc.x += __shfl_xor(acc.x, 32);
  acc.y += __shfl_xor(acc.y, 32);
  if (half == 0) {
    __hip_bfloat162 o;
    o.x = __float2bfloat16(fmaxf(acc.x, 0.f));
    o.y = __float2bfloat16(fmaxf(acc.y, 0.f));
    ((__hip_bfloat162*)(y + (size_t)r * HID))[hl] = o;
  }
}

// ---------------- Linear2: LDS-staged like lin1 ------------------------------
__global__ __launch_bounds__(256) void lin2_kernel(
    const bf16* __restrict__ yin, const float* __restrict__ W2,
    const float* __restrict__ b2, bf16* __restrict__ xout, int n) {
  __shared__ float sW4[(HID / 4) * HID * 4];   // 16 KB
  __shared__ float sE[NPB * 68];               // 8.7 KB
  const int t = threadIdx.x;
  for (int i = t; i < HID * HID; i += 256) {
    int k = i >> 6, f = i & 63;
    sW4[((k >> 2) * HID + f) * 4 + (k & 3)] = W2[i];
  }
  const int base = blockIdx.x * NPB;
  if (base + NPB <= n) {
    const ushort4* yv = (const ushort4*)(yin + (size_t)base * HID);
    for (int i = t; i < NPB * (HID / 4); i += 256) {
      int nn = i >> 4, k4 = i & 15;
      ushort4 u = yv[i];
      float4 v;
      v.x = bf2f(u.x); v.y = bf2f(u.y); v.z = bf2f(u.z); v.w = bf2f(u.w);
      *(float4*)&sE[nn * 68 + 4 * k4] = v;
    }
  } else {
    for (int i = t; i < NPB * HID; i += 256) {
      int nn = i >> 6, k = i & 63;
      int node = base + nn;
      sE[nn * 68 + k] = (node < n) ? __bfloat162float(yin[(size_t)node * HID + k]) : 0.f;
    }
  }
  __syncthreads();

  const int lane = t & 63, g = t >> 6;
  float a[8] = {};
#pragma unroll 4
  for (int k4 = 0; k4 < HID / 4; ++k4) {
    const float4 w = *(const float4*)&sW4[(k4 * HID + lane) * 4];
#pragma unroll
    for (int j = 0; j < 8; ++j) {
      const float4 e = *(const float4*)&sE[(g * 8 + j) * 68 + 4 * k4];
      a[j] += e.x * w.x + e.y * w.y + e.z * w.z + e.w * w.w;
    }
  }
  const float bias = b2[lane];
#pragma unroll
  for (int j = 0; j < 8; ++j) {
    const int node = base + g * 8 + j;
    if (node >= n) break;
    xout[(size_t)node * HID + lane] = __float2bfloat16(a[j] + bias);
  }
}

// ---------------- SpMM2 + fused ReLU + Wout-dot -> per-block partial ---------
__global__ __launch_bounds__(256) void spmm2_fused_kernel(
    const int* __restrict__ row_ptr, const int2* __restrict__ ce,
    const bf16* __restrict__ x, const float* __restrict__ Wout,
    float* __restrict__ partials, int n) {
  const int lane = threadIdx.x & 63;
  const int half = lane >> 5;
  const int hl   = lane & 31;
  const int g = threadIdx.x >> 6;
  const int r = blockIdx.x * 4 + g;
  float wpart = 0.f;
  if (r < n) {
    int i = row_ptr[r];
    const int end = row_ptr[r + 1];
    float2 acc = {0.f, 0.f};
    for (; i + 16 <= end; i += 16) {
      int2 e0 = ce[i],    e1 = ce[i+1],  e2 = ce[i+2],  e3 = ce[i+3];
      int2 e4 = ce[i+4],  e5 = ce[i+5],  e6 = ce[i+6],  e7 = ce[i+7];
      int2 e8 = ce[i+8],  e9 = ce[i+9],  ea = ce[i+10], eb = ce[i+11];
      int2 ec = ce[i+12], ed = ce[i+13], ee = ce[i+14], ef = ce[i+15];
      PAIR(e0, e1); PAIR(e2, e3); PAIR(e4, e5); PAIR(e6, e7);
      PAIR(e8, e9); PAIR(ea, eb); PAIR(ec, ed); PAIR(ee, ef);
    }
    for (; i + 2 <= end; i += 2) {
      int2 ea = ce[i], eb = ce[i + 1];
      PAIR(ea, eb);
    }
    if (i < end) {
      int2 ea = ce[i];
      const int   c = ea.x;
      const float v = half ? 0.f : __int_as_float(ea.y);
      const ushort2 u = *(const ushort2*)((const unsigned short*)x +
                                          ((size_t)c << 6) + (hl << 1));
      acc.x += v * bf2f(u.x);
      acc.y += v * bf2f(u.y);
    }
    acc.x += __shfl_xor(acc.x, 32);
    acc.y += __shfl_xor(acc.y, 32);
    if (half == 0) {
      const float2 wv = ((const float2*)Wout)[hl];
      wpart = fmaxf(acc.x, 0.f) * wv.x + fmaxf(acc.y, 0.f) * wv.y;
    }
  }
  for (int off = 32; off; off >>= 1) wpart += __shfl_down(wpart, off, 64);
  __shared__ float part[4];
  if (lane == 0) part[g] = wpart;
  __syncthreads();
  if (threadIdx.x == 0)
    partials[blockIdx.x] = part[0] + part[1] + part[2] + part[3];   // plain store
}

// ---------------- final: sum 25k partials (1 block) --------------------------
__global__ __launch_bounds__(1024) void reduce_kernel(
    const float* __restrict__ partials, const float* __restrict__ bout,
    float* __restrict__ out, int m) {
  const int t = threadIdx.x;
  float s = 0.f;
  for (int i = t; i < m; i += 1024) s += partials[i];
  for (int off = 32; off; off >>= 1) s += __shfl_down(s, off, 64);
  __shared__ float wsum[16];
  if ((t & 63) == 0) wsum[t >> 6] = s;
  __syncthreads();
  if (t == 0) {
    float tot = bout[0];
    for (int w = 0; w < 16; ++w) tot += wsum[w];
    out[0] = tot;
  }
}

extern "C" void kernel_launch(void* const* d_in, const int* in_sizes, int n_in,
                              void* d_out, int out_size, void* d_ws, size_t ws_size,
                              hipStream_t stream) {
  const float* emb  = (const float*)d_in[0];
  const float* deg  = (const float*)d_in[1];
  const float* seed = (const float*)d_in[2];
  const int*   row  = (const int*)d_in[3];
  const int*   col  = (const int*)d_in[4];
  const float* vals = (const float*)d_in[5];
  const float* W1   = (const float*)d_in[6];
  const float* b1   = (const float*)d_in[7];
  const float* W2   = (const float*)d_in[8];
  const float* b2   = (const float*)d_in[9];
  const float* Wout = (const float*)d_in[10];
  const float* bout = (const float*)d_in[11];
  float* out = (float*)d_out;

  const int n  = in_sizes[0] / IN_EMB;   // 100000
  const int nE = in_sizes[3];            // 3200000
  const int nbkt = (n + ROWS_PER_BKT - 1) / ROWS_PER_BKT;   // 782

  const int node_blocks = (n + NPB - 1) / NPB;
  const int row_blocks  = (n + 3) / 4;
  const int part_blocks = (nE + PART_CHUNK - 1) / PART_CHUNK;

  // ---- workspace layout ----
  char* ws = (char*)d_ws;
  int2* ce   = (int2*)ws;  ws += (size_t)nE * sizeof(int2);             // live to end
  char* tmpb = ws;
  int2* tmp  = (int2*)ws;  ws += (size_t)nE * sizeof(int2);             // dead after sort
  bf16* xa   = (bf16*)ws;  ws += ((size_t)n * HID * 2 + 255) & ~255ULL;
  bf16* xb   = (bf16*)ws;  ws += ((size_t)n * HID * 2 + 255) & ~255ULL;
  int* row_ptr = (int*)ws; ws += ((size_t)(n + 1) * 4 + 255) & ~255ULL;
  int* bcnt    = (int*)ws; ws += ((size_t)nbkt * 4 + 255) & ~255ULL;
  int* bstart  = (int*)ws; ws += ((size_t)(nbkt + 1) * 4 + 255) & ~255ULL;
  int* bcur    = (int*)ws; ws += ((size_t)nbkt * 4 + 255) & ~255ULL;
  float* partials = (float*)ws;                                         // row_blocks floats
  bf16* ya = (bf16*)tmpb;   // alias: tmp dead before spmm1 writes ya

  // ---- CSR build ----
  hipMemsetAsync(bcnt, 0, (size_t)nbkt * sizeof(int), stream);
  bhist_kernel<<<512, 256, 0, stream>>>(row, bcnt, nE, nbkt);
  bscan_kernel<<<1, 1024, 0, stream>>>(bcnt, bstart, bcur, row_ptr, n, nbkt);
  partition_kernel<<<part_blocks, 256, 0, stream>>>(row, col, vals, bcur, tmp, nE);
  bucket_sort_kernel<<<nbkt, 256, 0, stream>>>(bstart, tmp, ce, row_ptr, n);

  // ---- network ----
  lin1_kernel<<<node_blocks, 256, 0, stream>>>(emb, deg, seed, W1, b1, xa, n);
  spmm_csr_kernel<<<row_blocks, 256, 0, stream>>>(row_ptr, ce, xa, ya, n);
  lin2_kernel<<<node_blocks, 256, 0, stream>>>(ya, W2, b2, xb, n);
  spmm2_fused_kernel<<<row_blocks, 256, 0, stream>>>(row_ptr, ce, xb, Wout, partials, n);
  reduce_kernel<<<1, 1024, 0, stream>>>(partials, bout, out, row_blocks);
}

// Round 7
// 518.339 us; speedup vs baseline: 1.6100x; 1.1444x over previous
//
#include <hip/hip_runtime.h>
#include <hip/hip_bf16.h>

#define HID 64
#define IN_EMB 128
#define IN_DIM 130
#define ROWS_PER_BKT 128
#define LOG_RPB 7
#define MAX_BKT 1024          // 100000/128 = 782 buckets actually used
#define PART_CHUNK 16384      // edges per partition block
#define ASTR 168              // lin1 LDS row stride (shorts): 16B-aligned, bank-spread
#define BSTR 72               // lin2 LDS row stride (shorts)

typedef __hip_bfloat16 bf16;
typedef __attribute__((ext_vector_type(8))) short bf16x8;
typedef __attribute__((ext_vector_type(4))) float fx4;

__device__ __forceinline__ float bf2f(unsigned short u) {
  return __uint_as_float((unsigned)u << 16);
}
__device__ __forceinline__ short f2bfs(float f) {
  __hip_bfloat16 h = __float2bfloat16(f);
  return *(reinterpret_cast<short*>(&h));
}

// ---------------- coarse histogram over row-buckets --------------------------
__global__ __launch_bounds__(256) void bhist_kernel(const int* __restrict__ row,
                                                    int* __restrict__ bcnt,
                                                    int nE, int nbkt) {
  __shared__ int h[MAX_BKT];
  for (int i = threadIdx.x; i < nbkt; i += 256) h[i] = 0;
  __syncthreads();
  const int stride = gridDim.x * 256;
  for (int e = blockIdx.x * 256 + threadIdx.x; e < nE; e += stride)
    atomicAdd(&h[row[e] >> LOG_RPB], 1);
  __syncthreads();
  for (int i = threadIdx.x; i < nbkt; i += 256)
    if (h[i]) atomicAdd(&bcnt[i], h[i]);
}

// ---------------- exclusive scan of bucket counts (1 block) ------------------
__global__ __launch_bounds__(1024) void bscan_kernel(const int* __restrict__ bcnt,
                                                     int* __restrict__ bstart,
                                                     int* __restrict__ bcur,
                                                     int* __restrict__ row_ptr,
                                                     int n, int nbkt) {
  __shared__ int s[1024];
  const int t = threadIdx.x;
  const int v = (t < nbkt) ? bcnt[t] : 0;
  s[t] = v;
  __syncthreads();
  for (int off = 1; off < 1024; off <<= 1) {
    int u = (t >= off) ? s[t - off] : 0;
    __syncthreads();
    s[t] += u;
    __syncthreads();
  }
  if (t < nbkt) { int ex = s[t] - v; bstart[t] = ex; bcur[t] = ex; }
  if (t == 0) { bstart[nbkt] = s[1023]; row_ptr[n] = s[1023]; }   // == nE
}

// ---------------- partition edges into row-buckets (coalesced runs) ----------
// packed edge: .x = col | (local_row << 20), .y = bits(val)
__global__ __launch_bounds__(256) void partition_kernel(
    const int* __restrict__ row, const int* __restrict__ col,
    const float* __restrict__ vals, int* __restrict__ bcur,
    int2* __restrict__ tmp, int nE) {
  __shared__ int h[MAX_BKT];
  __shared__ int cur[MAX_BKT];
  const int t = threadIdx.x;
  const int base = blockIdx.x * PART_CHUNK;
  for (int i = t; i < MAX_BKT; i += 256) h[i] = 0;
  __syncthreads();
  for (int k = 0; k < PART_CHUNK / 256; ++k) {
    int e = base + k * 256 + t;
    if (e < nE) atomicAdd(&h[row[e] >> LOG_RPB], 1);
  }
  __syncthreads();
  for (int b = t; b < MAX_BKT; b += 256)
    if (h[b] > 0) cur[b] = atomicAdd(&bcur[b], h[b]);
  __syncthreads();
  for (int k = 0; k < PART_CHUNK / 256; ++k) {
    int e = base + k * 256 + t;
    if (e < nE) {
      int r = row[e];
      int b = r >> LOG_RPB;
      int p = atomicAdd(&cur[b], 1);
      tmp[p] = make_int2(col[e] | ((r & (ROWS_PER_BKT - 1)) << 20),
                         __float_as_int(vals[e]));
    }
  }
}

// ---------------- per-bucket counting sort -> exact CSR + row_ptr ------------
__global__ __launch_bounds__(256) void bucket_sort_kernel(
    const int* __restrict__ bstart, const int2* __restrict__ tmp,
    int2* __restrict__ ce, int* __restrict__ row_ptr, int n) {
  __shared__ int rcnt[ROWS_PER_BKT];
  __shared__ int rpos[ROWS_PER_BKT];
  __shared__ int sc[ROWS_PER_BKT];
  const int t = threadIdx.x;
  const int b = blockIdx.x;
  const int start = bstart[b];
  const int end   = bstart[b + 1];
  if (t < ROWS_PER_BKT) rcnt[t] = 0;
  __syncthreads();
  for (int i = start + t; i < end; i += 256)
    atomicAdd(&rcnt[tmp[i].x >> 20], 1);
  __syncthreads();
  if (t < ROWS_PER_BKT) sc[t] = rcnt[t];
  __syncthreads();
  for (int off = 1; off < ROWS_PER_BKT; off <<= 1) {
    int u = (t < ROWS_PER_BKT && t >= off) ? sc[t - off] : 0;
    __syncthreads();
    if (t < ROWS_PER_BKT) sc[t] += u;
    __syncthreads();
  }
  if (t < ROWS_PER_BKT) {
    int ex = sc[t] - rcnt[t];
    int gpos = start + ex;
    rpos[t] = gpos;
    int gr = b * ROWS_PER_BKT + t;
    if (gr < n) row_ptr[gr] = gpos;
  }
  __syncthreads();
  for (int i = start + t; i < end; i += 256) {
    int2 e = tmp[i];
    int p = atomicAdd(&rpos[e.x >> 20], 1);
    ce[p] = make_int2(e.x & 0xFFFFF, e.y);
  }
}

// ---------------- Linear1 via MFMA: [64 nodes x 160k] @ [160k x 64] ----------
// A-frag: A[m=lane&15][k=quad*8+j]; B-frag: B[k=quad*8+j][n=lane&15];
// D: col=lane&15, row=quad*4+reg  (m89/m91-verified layouts)
__global__ __launch_bounds__(256) void lin1_kernel(
    const float* __restrict__ emb, const float* __restrict__ deg,
    const float* __restrict__ seed, const float* __restrict__ W1,
    const float* __restrict__ b1, bf16* __restrict__ out, int n) {
  __shared__ short sA[64 * ASTR];   // 21 KB: x-tile bf16, K padded to 160
  __shared__ short sB[64 * ASTR];   // 21 KB: W1^T bf16 [n][k]
  const int t = threadIdx.x;
  const int base = blockIdx.x * 64;

  // stage W1^T: sB[nn][k] = W1[k][nn]; zero-pad k in [130,160)
  for (int idx = t; idx < 64 * 160; idx += 256) {
    int k = idx >> 6, nn = idx & 63;
    float v = (k < IN_DIM) ? W1[k * HID + nn] : 0.f;
    sB[nn * ASTR + k] = f2bfs(v);
  }
  // stage A, k<128: emb (coalesced float4), bf16-convert
  for (int idx = t; idx < 64 * 32; idx += 256) {
    int nn = idx >> 5, k4 = idx & 31;
    int node = base + nn;
    short4 w;
    if (node < n) {
      float4 v = ((const float4*)emb)[(size_t)node * 32 + k4];
      w = make_short4(f2bfs(v.x), f2bfs(v.y), f2bfs(v.z), f2bfs(v.w));
    } else {
      w = make_short4(0, 0, 0, 0);
    }
    *(short4*)&sA[nn * ASTR + 4 * k4] = w;
  }
  // stage A, k in [128,160): deg, seed, zero-pad
  for (int idx = t; idx < 64 * 32; idx += 256) {
    int nn = idx >> 5, kk = idx & 31;
    int node = base + nn;
    float v = 0.f;
    if (node < n) {
      if (kk == 0) v = deg[node];
      else if (kk == 1) v = seed[node];
    }
    sA[nn * ASTR + 128 + kk] = f2bfs(v);
  }
  __syncthreads();

  const int lane = t & 63, w = t >> 6;
  const int nl = lane & 15, q = lane >> 4;
  const short* pA = &sA[(w * 16 + nl) * ASTR + q * 8];
  const short* pB = &sB[nl * ASTR + q * 8];
  fx4 ac0 = {0.f, 0.f, 0.f, 0.f}, ac1 = ac0, ac2 = ac0, ac3 = ac0;
#pragma unroll
  for (int kt = 0; kt < 5; ++kt) {
    bf16x8 a   = *(const bf16x8*)(pA + kt * 32);
    bf16x8 b0  = *(const bf16x8*)(pB + kt * 32);
    bf16x8 b1v = *(const bf16x8*)(pB + 16 * ASTR + kt * 32);
    bf16x8 b2v = *(const bf16x8*)(pB + 32 * ASTR + kt * 32);
    bf16x8 b3v = *(const bf16x8*)(pB + 48 * ASTR + kt * 32);
    ac0 = __builtin_amdgcn_mfma_f32_16x16x32_bf16(a, b0,  ac0, 0, 0, 0);
    ac1 = __builtin_amdgcn_mfma_f32_16x16x32_bf16(a, b1v, ac1, 0, 0, 0);
    ac2 = __builtin_amdgcn_mfma_f32_16x16x32_bf16(a, b2v, ac2, 0, 0, 0);
    ac3 = __builtin_amdgcn_mfma_f32_16x16x32_bf16(a, b3v, ac3, 0, 0, 0);
  }
  const float bias0 = b1[nl], bias1 = b1[16 + nl],
              bias2 = b1[32 + nl], bias3 = b1[48 + nl];
#pragma unroll
  for (int r = 0; r < 4; ++r) {
    int node = base + w * 16 + q * 4 + r;
    if (node < n) {
      bf16* o = out + (size_t)node * HID;
      o[nl]      = __float2bfloat16(ac0[r] + bias0);
      o[16 + nl] = __float2bfloat16(ac1[r] + bias1);
      o[32 + nl] = __float2bfloat16(ac2[r] + bias2);
      o[48 + nl] = __float2bfloat16(ac3[r] + bias3);
    }
  }
}

// ---- pair-gather: lanes 0-31 take edge A, lanes 32-63 edge B; ushort2/lane --
#define PAIR(ea, eb)                                                          \
  {                                                                           \
    const int   c = half ? (eb).x : (ea).x;                                   \
    const float v = __int_as_float(half ? (eb).y : (ea).y);                   \
    const ushort2 u = *(const ushort2*)((const unsigned short*)x +            \
                                        ((size_t)c << 6) + (hl << 1));        \
    acc.x += v * bf2f(u.x);                                                   \
    acc.y += v * bf2f(u.y);                                                   \
  }

// ---------------- SpMM1 (exact CSR, pair-gather) + fused ReLU ----------------
__global__ __launch_bounds__(256) void spmm_csr_kernel(
    const int* __restrict__ row_ptr, const int2* __restrict__ ce,
    const bf16* __restrict__ x, bf16* __restrict__ y, int n) {
  const int lane = threadIdx.x & 63;
  const int half = lane >> 5;
  const int hl   = lane & 31;
  const int r = blockIdx.x * 4 + (threadIdx.x >> 6);
  if (r >= n) return;
  int i = row_ptr[r];
  const int end = row_ptr[r + 1];
  float2 acc = {0.f, 0.f};
  for (; i + 16 <= end; i += 16) {
    int2 e0 = ce[i],    e1 = ce[i+1],  e2 = ce[i+2],  e3 = ce[i+3];
    int2 e4 = ce[i+4],  e5 = ce[i+5],  e6 = ce[i+6],  e7 = ce[i+7];
    int2 e8 = ce[i+8],  e9 = ce[i+9],  ea = ce[i+10], eb = ce[i+11];
    int2 ec = ce[i+12], ed = ce[i+13], ee = ce[i+14], ef = ce[i+15];
    PAIR(e0, e1); PAIR(e2, e3); PAIR(e4, e5); PAIR(e6, e7);
    PAIR(e8, e9); PAIR(ea, eb); PAIR(ec, ed); PAIR(ee, ef);
  }
  for (; i + 2 <= end; i += 2) {
    int2 ea = ce[i], eb = ce[i + 1];
    PAIR(ea, eb);
  }
  if (i < end) {
    int2 ea = ce[i];
    const int   c = ea.x;
    const float v = half ? 0.f : __int_as_float(ea.y);
    const ushort2 u = *(const ushort2*)((const unsigned short*)x +
                                        ((size_t)c << 6) + (hl << 1));
    acc.x += v * bf2f(u.x);
    acc.y += v * bf2f(u.y);
  }
  acc.x += __shfl_xor(acc.x, 32);
  acc.y += __shfl_xor(acc.y, 32);
  if (half == 0) {
    __hip_bfloat162 o;
    o.x = __float2bfloat16(fmaxf(acc.x, 0.f));
    o.y = __float2bfloat16(fmaxf(acc.y, 0.f));
    ((__hip_bfloat162*)(y + (size_t)r * HID))[hl] = o;
  }
}

// ---------------- Linear2 via MFMA: [64 nodes x 64] @ [64 x 64] --------------
// A-frags straight from global (bf16, 16B/lane segment-coalesced); W2^T in LDS.
__global__ __launch_bounds__(256) void lin2_kernel(
    const bf16* __restrict__ yin, const float* __restrict__ W2,
    const float* __restrict__ b2, bf16* __restrict__ xout, int n) {
  __shared__ short sB[64 * BSTR];   // 9 KB: W2^T bf16 [n][k]
  const int t = threadIdx.x;
  const int base = blockIdx.x * 64;
  for (int idx = t; idx < 64 * 64; idx += 256) {
    int k = idx >> 6, nn = idx & 63;
    sB[nn * BSTR + k] = f2bfs(W2[k * HID + nn]);
  }
  __syncthreads();

  const int lane = t & 63, w = t >> 6;
  const int nl = lane & 15, q = lane >> 4;
  // A row: node = base + w*16 + nl (OOB rows read mapped ws garbage; stores masked)
  const short* xg = (const short*)yin + ((size_t)(base + w * 16 + nl)) * HID + q * 8;
  const short* pB = &sB[nl * BSTR + q * 8];
  fx4 ac0 = {0.f, 0.f, 0.f, 0.f}, ac1 = ac0, ac2 = ac0, ac3 = ac0;
#pragma unroll
  for (int kt = 0; kt < 2; ++kt) {
    bf16x8 a   = *(const bf16x8*)(xg + kt * 32);
    bf16x8 b0  = *(const bf16x8*)(pB + kt * 32);
    bf16x8 b1v = *(const bf16x8*)(pB + 16 * BSTR + kt * 32);
    bf16x8 b2v = *(const bf16x8*)(pB + 32 * BSTR + kt * 32);
    bf16x8 b3v = *(const bf16x8*)(pB + 48 * BSTR + kt * 32);
    ac0 = __builtin_amdgcn_mfma_f32_16x16x32_bf16(a, b0,  ac0, 0, 0, 0);
    ac1 = __builtin_amdgcn_mfma_f32_16x16x32_bf16(a, b1v, ac1, 0, 0, 0);
    ac2 = __builtin_amdgcn_mfma_f32_16x16x32_bf16(a, b2v, ac2, 0, 0, 0);
    ac3 = __builtin_amdgcn_mfma_f32_16x16x32_bf16(a, b3v, ac3, 0, 0, 0);
  }
  const float bias0 = b2[nl], bias1 = b2[16 + nl],
              bias2 = b2[32 + nl], bias3 = b2[48 + nl];
#pragma unroll
  for (int r = 0; r < 4; ++r) {
    int node = base + w * 16 + q * 4 + r;
    if (node < n) {
      bf16* o = xout + (size_t)node * HID;
      o[nl]      = __float2bfloat16(ac0[r] + bias0);
      o[16 + nl] = __float2bfloat16(ac1[r] + bias1);
      o[32 + nl] = __float2bfloat16(ac2[r] + bias2);
      o[48 + nl] = __float2bfloat16(ac3[r] + bias3);
    }
  }
}

// ---------------- SpMM2 + fused ReLU + Wout-dot -> per-block partial ---------
__global__ __launch_bounds__(256) void spmm2_fused_kernel(
    const int* __restrict__ row_ptr, const int2* __restrict__ ce,
    const bf16* __restrict__ x, const float* __restrict__ Wout,
    float* __restrict__ partials, int n) {
  const int lane = threadIdx.x & 63;
  const int half = lane >> 5;
  const int hl   = lane & 31;
  const int g = threadIdx.x >> 6;
  const int r = blockIdx.x * 4 + g;
  float wpart = 0.f;
  if (r < n) {
    int i = row_ptr[r];
    const int end = row_ptr[r + 1];
    float2 acc = {0.f, 0.f};
    for (; i + 16 <= end; i += 16) {
      int2 e0 = ce[i],    e1 = ce[i+1],  e2 = ce[i+2],  e3 = ce[i+3];
      int2 e4 = ce[i+4],  e5 = ce[i+5],  e6 = ce[i+6],  e7 = ce[i+7];
      int2 e8 = ce[i+8],  e9 = ce[i+9],  ea = ce[i+10], eb = ce[i+11];
      int2 ec = ce[i+12], ed = ce[i+13], ee = ce[i+14], ef = ce[i+15];
      PAIR(e0, e1); PAIR(e2, e3); PAIR(e4, e5); PAIR(e6, e7);
      PAIR(e8, e9); PAIR(ea, eb); PAIR(ec, ed); PAIR(ee, ef);
    }
    for (; i + 2 <= end; i += 2) {
      int2 ea = ce[i], eb = ce[i + 1];
      PAIR(ea, eb);
    }
    if (i < end) {
      int2 ea = ce[i];
      const int   c = ea.x;
      const float v = half ? 0.f : __int_as_float(ea.y);
      const ushort2 u = *(const ushort2*)((const unsigned short*)x +
                                          ((size_t)c << 6) + (hl << 1));
      acc.x += v * bf2f(u.x);
      acc.y += v * bf2f(u.y);
    }
    acc.x += __shfl_xor(acc.x, 32);
    acc.y += __shfl_xor(acc.y, 32);
    if (half == 0) {
      const float2 wv = ((const float2*)Wout)[hl];
      wpart = fmaxf(acc.x, 0.f) * wv.x + fmaxf(acc.y, 0.f) * wv.y;
    }
  }
  for (int off = 32; off; off >>= 1) wpart += __shfl_down(wpart, off, 64);
  __shared__ float part[4];
  if (lane == 0) part[g] = wpart;
  __syncthreads();
  if (threadIdx.x == 0)
    partials[blockIdx.x] = part[0] + part[1] + part[2] + part[3];
}

// ---------------- final: sum 25k partials (1 block) --------------------------
__global__ __launch_bounds__(1024) void reduce_kernel(
    const float* __restrict__ partials, const float* __restrict__ bout,
    float* __restrict__ out, int m) {
  const int t = threadIdx.x;
  float s = 0.f;
  for (int i = t; i < m; i += 1024) s += partials[i];
  for (int off = 32; off; off >>= 1) s += __shfl_down(s, off, 64);
  __shared__ float wsum[16];
  if ((t & 63) == 0) wsum[t >> 6] = s;
  __syncthreads();
  if (t == 0) {
    float tot = bout[0];
    for (int w = 0; w < 16; ++w) tot += wsum[w];
    out[0] = tot;
  }
}

extern "C" void kernel_launch(void* const* d_in, const int* in_sizes, int n_in,
                              void* d_out, int out_size, void* d_ws, size_t ws_size,
                              hipStream_t stream) {
  const float* emb  = (const float*)d_in[0];
  const float* deg  = (const float*)d_in[1];
  const float* seed = (const float*)d_in[2];
  const int*   row  = (const int*)d_in[3];
  const int*   col  = (const int*)d_in[4];
  const float* vals = (const float*)d_in[5];
  const float* W1   = (const float*)d_in[6];
  const float* b1   = (const float*)d_in[7];
  const float* W2   = (const float*)d_in[8];
  const float* b2   = (const float*)d_in[9];
  const float* Wout = (const float*)d_in[10];
  const float* bout = (const float*)d_in[11];
  float* out = (float*)d_out;

  const int n  = in_sizes[0] / IN_EMB;   // 100000
  const int nE = in_sizes[3];            // 3200000
  const int nbkt = (n + ROWS_PER_BKT - 1) / ROWS_PER_BKT;   // 782

  const int lin_blocks  = (n + 63) / 64;
  const int row_blocks  = (n + 3) / 4;
  const int part_blocks = (nE + PART_CHUNK - 1) / PART_CHUNK;

  // ---- workspace layout ----
  char* ws = (char*)d_ws;
  int2* ce   = (int2*)ws;  ws += (size_t)nE * sizeof(int2);             // live to end
  char* tmpb = ws;
  int2* tmp  = (int2*)ws;  ws += (size_t)nE * sizeof(int2);             // dead after sort
  bf16* xa   = (bf16*)ws;  ws += ((size_t)n * HID * 2 + 255) & ~255ULL;
  bf16* xb   = (bf16*)ws;  ws += ((size_t)n * HID * 2 + 255) & ~255ULL;
  int* row_ptr = (int*)ws; ws += ((size_t)(n + 1) * 4 + 255) & ~255ULL;
  int* bcnt    = (int*)ws; ws += ((size_t)nbkt * 4 + 255) & ~255ULL;
  int* bstart  = (int*)ws; ws += ((size_t)(nbkt + 1) * 4 + 255) & ~255ULL;
  int* bcur    = (int*)ws; ws += ((size_t)nbkt * 4 + 255) & ~255ULL;
  float* partials = (float*)ws;                                         // row_blocks floats
  bf16* ya = (bf16*)tmpb;   // alias: tmp dead before spmm1 writes ya

  // ---- CSR build ----
  hipMemsetAsync(bcnt, 0, (size_t)nbkt * sizeof(int), stream);
  bhist_kernel<<<512, 256, 0, stream>>>(row, bcnt, nE, nbkt);
  bscan_kernel<<<1, 1024, 0, stream>>>(bcnt, bstart, bcur, row_ptr, n, nbkt);
  partition_kernel<<<part_blocks, 256, 0, stream>>>(row, col, vals, bcur, tmp, nE);
  bucket_sort_kernel<<<nbkt, 256, 0, stream>>>(bstart, tmp, ce, row_ptr, n);

  // ---- network ----
  lin1_kernel<<<lin_blocks, 256, 0, stream>>>(emb, deg, seed, W1, b1, xa, n);
  spmm_csr_kernel<<<row_blocks, 256, 0, stream>>>(row_ptr, ce, xa, ya, n);
  lin2_kernel<<<lin_blocks, 256, 0, stream>>>(ya, W2, b2, xb, n);
  spmm2_fused_kernel<<<row_blocks, 256, 0, stream>>>(row_ptr, ce, xb, Wout, partials, n);
  reduce_kernel<<<1, 1024, 0, stream>>>(partials, bout, out, row_blocks);
}

// Round 8
// 456.335 us; speedup vs baseline: 1.8287x; 1.1359x over previous
//
#include <hip/hip_runtime.h>
#include <hip/hip_bf16.h>

#define HID 64
#define IN_EMB 128
#define IN_DIM 130
#define ROWS_PER_BKT 128
#define LOG_RPB 7
#define MAX_BKT 1024          // 100000/128 = 782 buckets actually used
#define PART_CHUNK 4096       // edges per partition block (782 blocks)
#define ASTR 168              // lin1 LDS row stride (shorts)
#define BSTR 72               // lin2 LDS row stride (shorts)

typedef __hip_bfloat16 bf16;
typedef __attribute__((ext_vector_type(8))) short bf16x8;
typedef __attribute__((ext_vector_type(4))) float fx4;

__device__ __forceinline__ float bf2f(unsigned short u) {
  return __uint_as_float((unsigned)u << 16);
}
__device__ __forceinline__ short f2bfs(float f) {
  __hip_bfloat16 h = __float2bfloat16(f);
  return *(reinterpret_cast<short*>(&h));
}

// ---------------- coarse histogram over row-buckets (int4 loads) -------------
__global__ __launch_bounds__(256) void bhist_kernel(const int* __restrict__ row,
                                                    int* __restrict__ bcnt,
                                                    int nE, int nbkt) {
  __shared__ int h[MAX_BKT];
  for (int i = threadIdx.x; i < MAX_BKT; i += 256) h[i] = 0;
  __syncthreads();
  const int tot4 = nE >> 2;
  const int stride = gridDim.x * 256;
  for (int idx = blockIdx.x * 256 + threadIdx.x; idx < tot4; idx += stride) {
    int4 r4 = ((const int4*)row)[idx];
    atomicAdd(&h[r4.x >> LOG_RPB], 1);
    atomicAdd(&h[r4.y >> LOG_RPB], 1);
    atomicAdd(&h[r4.z >> LOG_RPB], 1);
    atomicAdd(&h[r4.w >> LOG_RPB], 1);
  }
  if (blockIdx.x == 0 && threadIdx.x < (nE & 3))
    atomicAdd(&h[row[(nE & ~3) + threadIdx.x] >> LOG_RPB], 1);
  __syncthreads();
  for (int i = threadIdx.x; i < nbkt; i += 256)
    if (h[i]) atomicAdd(&bcnt[i], h[i]);
}

// ---------------- exclusive scan of bucket counts (1 block) ------------------
__global__ __launch_bounds__(1024) void bscan_kernel(const int* __restrict__ bcnt,
                                                     int* __restrict__ bstart,
                                                     int* __restrict__ bcur,
                                                     int* __restrict__ row_ptr,
                                                     int n, int nbkt) {
  __shared__ int s[1024];
  const int t = threadIdx.x;
  const int v = (t < nbkt) ? bcnt[t] : 0;
  s[t] = v;
  __syncthreads();
  for (int off = 1; off < 1024; off <<= 1) {
    int u = (t >= off) ? s[t - off] : 0;
    __syncthreads();
    s[t] += u;
    __syncthreads();
  }
  if (t < nbkt) { int ex = s[t] - v; bstart[t] = ex; bcur[t] = ex; }
  if (t == 0) { bstart[nbkt] = s[1023]; row_ptr[n] = s[1023]; }   // == nE
}

// ---------------- partition edges into row-buckets (vectorized, 512T) --------
// packed edge: .x = col | (local_row << 20), .y = bits(val)
__global__ __launch_bounds__(512) void partition_kernel(
    const int* __restrict__ row, const int* __restrict__ col,
    const float* __restrict__ vals, int* __restrict__ bcur,
    int2* __restrict__ tmp, int nE) {
  __shared__ int h[MAX_BKT];
  __shared__ int cur[MAX_BKT];
  const int t = threadIdx.x;
  const int base = blockIdx.x * PART_CHUNK;      // multiple of 4096
  for (int i = t; i < MAX_BKT; i += 512) h[i] = 0;
  __syncthreads();
  // phase A: local bucket histogram (int4)
  for (int kk = t; kk < PART_CHUNK / 4; kk += 512) {
    int e0 = base + kk * 4;
    if (e0 + 3 < nE) {
      int4 r4 = ((const int4*)row)[(base >> 2) + kk];
      atomicAdd(&h[r4.x >> LOG_RPB], 1);
      atomicAdd(&h[r4.y >> LOG_RPB], 1);
      atomicAdd(&h[r4.z >> LOG_RPB], 1);
      atomicAdd(&h[r4.w >> LOG_RPB], 1);
    } else {
      for (int j = 0; j < 4; ++j) {
        int e = e0 + j;
        if (e < nE) atomicAdd(&h[row[e] >> LOG_RPB], 1);
      }
    }
  }
  __syncthreads();
  // phase B: reserve contiguous runs
  for (int b = t; b < MAX_BKT; b += 512)
    if (h[b] > 0) cur[b] = atomicAdd(&bcur[b], h[b]);
  __syncthreads();
  // phase C: re-read, write grouped
  for (int kk = t; kk < PART_CHUNK / 4; kk += 512) {
    int e0 = base + kk * 4;
    if (e0 + 3 < nE) {
      int4 r4 = ((const int4*)row)[(base >> 2) + kk];
      int4 c4 = ((const int4*)col)[(base >> 2) + kk];
      float4 v4 = ((const float4*)vals)[(base >> 2) + kk];
      int rr[4] = {r4.x, r4.y, r4.z, r4.w};
      int cc[4] = {c4.x, c4.y, c4.z, c4.w};
      float vv[4] = {v4.x, v4.y, v4.z, v4.w};
#pragma unroll
      for (int j = 0; j < 4; ++j) {
        int b = rr[j] >> LOG_RPB;
        int p = atomicAdd(&cur[b], 1);
        tmp[p] = make_int2(cc[j] | ((rr[j] & (ROWS_PER_BKT - 1)) << 20),
                           __float_as_int(vv[j]));
      }
    } else {
      for (int j = 0; j < 4; ++j) {
        int e = e0 + j;
        if (e < nE) {
          int r = row[e];
          int b = r >> LOG_RPB;
          int p = atomicAdd(&cur[b], 1);
          tmp[p] = make_int2(col[e] | ((r & (ROWS_PER_BKT - 1)) << 20),
                             __float_as_int(vals[e]));
        }
      }
    }
  }
}

// ---------------- per-bucket counting sort -> exact CSR + row_ptr (512T) -----
__global__ __launch_bounds__(512) void bucket_sort_kernel(
    const int* __restrict__ bstart, const int2* __restrict__ tmp,
    int2* __restrict__ ce, int* __restrict__ row_ptr, int n) {
  __shared__ int rcnt[ROWS_PER_BKT];
  __shared__ int rpos[ROWS_PER_BKT];
  __shared__ int sc[ROWS_PER_BKT];
  const int t = threadIdx.x;
  const int b = blockIdx.x;
  const int start = bstart[b];
  const int end   = bstart[b + 1];
  if (t < ROWS_PER_BKT) rcnt[t] = 0;
  __syncthreads();
  for (int i = start + t; i < end; i += 512)
    atomicAdd(&rcnt[tmp[i].x >> 20], 1);
  __syncthreads();
  if (t < ROWS_PER_BKT) sc[t] = rcnt[t];
  __syncthreads();
  for (int off = 1; off < ROWS_PER_BKT; off <<= 1) {
    int u = (t < ROWS_PER_BKT && t >= off) ? sc[t - off] : 0;
    __syncthreads();
    if (t < ROWS_PER_BKT) sc[t] += u;
    __syncthreads();
  }
  if (t < ROWS_PER_BKT) {
    int ex = sc[t] - rcnt[t];
    int gpos = start + ex;
    rpos[t] = gpos;
    int gr = b * ROWS_PER_BKT + t;
    if (gr < n) row_ptr[gr] = gpos;
  }
  __syncthreads();
  for (int i = start + t; i < end; i += 512) {
    int2 e = tmp[i];
    int p = atomicAdd(&rpos[e.x >> 20], 1);
    ce[p] = make_int2(e.x & 0xFFFFF, e.y);
  }
}

// ---------------- Linear1 via MFMA -------------------------------------------
__global__ __launch_bounds__(256) void lin1_kernel(
    const float* __restrict__ emb, const float* __restrict__ deg,
    const float* __restrict__ seed, const float* __restrict__ W1,
    const float* __restrict__ b1, bf16* __restrict__ out, int n) {
  __shared__ short sA[64 * ASTR];
  __shared__ short sB[64 * ASTR];
  const int t = threadIdx.x;
  const int base = blockIdx.x * 64;

  for (int idx = t; idx < 64 * 160; idx += 256) {
    int k = idx >> 6, nn = idx & 63;
    float v = (k < IN_DIM) ? W1[k * HID + nn] : 0.f;
    sB[nn * ASTR + k] = f2bfs(v);
  }
  for (int idx = t; idx < 64 * 32; idx += 256) {
    int nn = idx >> 5, k4 = idx & 31;
    int node = base + nn;
    short4 w;
    if (node < n) {
      float4 v = ((const float4*)emb)[(size_t)node * 32 + k4];
      w = make_short4(f2bfs(v.x), f2bfs(v.y), f2bfs(v.z), f2bfs(v.w));
    } else {
      w = make_short4(0, 0, 0, 0);
    }
    *(short4*)&sA[nn * ASTR + 4 * k4] = w;
  }
  for (int idx = t; idx < 64 * 32; idx += 256) {
    int nn = idx >> 5, kk = idx & 31;
    int node = base + nn;
    float v = 0.f;
    if (node < n) {
      if (kk == 0) v = deg[node];
      else if (kk == 1) v = seed[node];
    }
    sA[nn * ASTR + 128 + kk] = f2bfs(v);
  }
  __syncthreads();

  const int lane = t & 63, w = t >> 6;
  const int nl = lane & 15, q = lane >> 4;
  const short* pA = &sA[(w * 16 + nl) * ASTR + q * 8];
  const short* pB = &sB[nl * ASTR + q * 8];
  fx4 ac0 = {0.f, 0.f, 0.f, 0.f}, ac1 = ac0, ac2 = ac0, ac3 = ac0;
#pragma unroll
  for (int kt = 0; kt < 5; ++kt) {
    bf16x8 a   = *(const bf16x8*)(pA + kt * 32);
    bf16x8 b0  = *(const bf16x8*)(pB + kt * 32);
    bf16x8 b1v = *(const bf16x8*)(pB + 16 * ASTR + kt * 32);
    bf16x8 b2v = *(const bf16x8*)(pB + 32 * ASTR + kt * 32);
    bf16x8 b3v = *(const bf16x8*)(pB + 48 * ASTR + kt * 32);
    ac0 = __builtin_amdgcn_mfma_f32_16x16x32_bf16(a, b0,  ac0, 0, 0, 0);
    ac1 = __builtin_amdgcn_mfma_f32_16x16x32_bf16(a, b1v, ac1, 0, 0, 0);
    ac2 = __builtin_amdgcn_mfma_f32_16x16x32_bf16(a, b2v, ac2, 0, 0, 0);
    ac3 = __builtin_amdgcn_mfma_f32_16x16x32_bf16(a, b3v, ac3, 0, 0, 0);
  }
  const float bias0 = b1[nl], bias1 = b1[16 + nl],
              bias2 = b1[32 + nl], bias3 = b1[48 + nl];
#pragma unroll
  for (int r = 0; r < 4; ++r) {
    int node = base + w * 16 + q * 4 + r;
    if (node < n) {
      bf16* o = out + (size_t)node * HID;
      o[nl]      = __float2bfloat16(ac0[r] + bias0);
      o[16 + nl] = __float2bfloat16(ac1[r] + bias1);
      o[32 + nl] = __float2bfloat16(ac2[r] + bias2);
      o[48 + nl] = __float2bfloat16(ac3[r] + bias3);
    }
  }
}

// ---- quad-gather: 4 edges per vmem; lane covers features [4*fl,4*fl+4) ------
#define QUAD(m0, m1, m2, m3)                                                  \
  {                                                                           \
    int2 eab = (sub & 1) ? (m1) : (m0);                                       \
    int2 ecd = (sub & 1) ? (m3) : (m2);                                       \
    const int   c = (sub & 2) ? ecd.x : eab.x;                                \
    const float v = __int_as_float((sub & 2) ? ecd.y : eab.y);                \
    const ushort4 u = *(const ushort4*)(xp + ((size_t)c << 6) + 4 * fl);      \
    acc.x += v * bf2f(u.x); acc.y += v * bf2f(u.y);                           \
    acc.z += v * bf2f(u.z); acc.w += v * bf2f(u.w);                           \
  }

#define QUAD_TAIL(i0base)                                                     \
  {                                                                           \
    int ei = (i0base) + sub;                                                  \
    bool ok = ei < end;                                                       \
    int2 e = ce[ok ? ei : end - 1];                                           \
    float v = ok ? __int_as_float(e.y) : 0.f;                                 \
    const ushort4 u = *(const ushort4*)(xp + ((size_t)e.x << 6) + 4 * fl);    \
    acc.x += v * bf2f(u.x); acc.y += v * bf2f(u.y);                           \
    acc.z += v * bf2f(u.z); acc.w += v * bf2f(u.w);                           \
  }

// ---------------- SpMM1 (exact CSR, quad-gather) + fused ReLU ----------------
__global__ __launch_bounds__(256) void spmm_csr_kernel(
    const int* __restrict__ row_ptr, const int2* __restrict__ ce,
    const bf16* __restrict__ x, bf16* __restrict__ y, int n) {
  const int lane = threadIdx.x & 63;
  const int sub = lane >> 4;
  const int fl  = lane & 15;
  const int r = blockIdx.x * 4 + (threadIdx.x >> 6);
  if (r >= n) return;
  const ushort* xp = (const ushort*)x;
  int i = row_ptr[r];
  const int end = row_ptr[r + 1];
  float4 acc = {0.f, 0.f, 0.f, 0.f};
  for (; i + 16 <= end; i += 16) {
    int2 m0 = ce[i],    m1 = ce[i+1],  m2 = ce[i+2],  m3 = ce[i+3];
    int2 m4 = ce[i+4],  m5 = ce[i+5],  m6 = ce[i+6],  m7 = ce[i+7];
    int2 m8 = ce[i+8],  m9 = ce[i+9],  ma = ce[i+10], mb = ce[i+11];
    int2 mc = ce[i+12], md = ce[i+13], me = ce[i+14], mf = ce[i+15];
    QUAD(m0, m1, m2, m3); QUAD(m4, m5, m6, m7);
    QUAD(m8, m9, ma, mb); QUAD(mc, md, me, mf);
  }
  for (; i < end; i += 8) {    // clamped tail, 2 quads per iter
    QUAD_TAIL(i);
    QUAD_TAIL(i + 4);
  }
  acc.x += __shfl_xor(acc.x, 16); acc.x += __shfl_xor(acc.x, 32);
  acc.y += __shfl_xor(acc.y, 16); acc.y += __shfl_xor(acc.y, 32);
  acc.z += __shfl_xor(acc.z, 16); acc.z += __shfl_xor(acc.z, 32);
  acc.w += __shfl_xor(acc.w, 16); acc.w += __shfl_xor(acc.w, 32);
  if (sub == 0) {
    short4 o = make_short4(f2bfs(fmaxf(acc.x, 0.f)), f2bfs(fmaxf(acc.y, 0.f)),
                           f2bfs(fmaxf(acc.z, 0.f)), f2bfs(fmaxf(acc.w, 0.f)));
    *(short4*)((short*)y + ((size_t)r << 6) + 4 * fl) = o;
  }
}

// ---------------- Linear2 via MFMA (A from global) ---------------------------
__global__ __launch_bounds__(256) void lin2_kernel(
    const bf16* __restrict__ yin, const float* __restrict__ W2,
    const float* __restrict__ b2, bf16* __restrict__ xout, int n) {
  __shared__ short sB[64 * BSTR];
  const int t = threadIdx.x;
  const int base = blockIdx.x * 64;
  for (int idx = t; idx < 64 * 64; idx += 256) {
    int k = idx >> 6, nn = idx & 63;
    sB[nn * BSTR + k] = f2bfs(W2[k * HID + nn]);
  }
  __syncthreads();

  const int lane = t & 63, w = t >> 6;
  const int nl = lane & 15, q = lane >> 4;
  const short* xg = (const short*)yin + ((size_t)(base + w * 16 + nl)) * HID + q * 8;
  const short* pB = &sB[nl * BSTR + q * 8];
  fx4 ac0 = {0.f, 0.f, 0.f, 0.f}, ac1 = ac0, ac2 = ac0, ac3 = ac0;
#pragma unroll
  for (int kt = 0; kt < 2; ++kt) {
    bf16x8 a   = *(const bf16x8*)(xg + kt * 32);
    bf16x8 b0  = *(const bf16x8*)(pB + kt * 32);
    bf16x8 b1v = *(const bf16x8*)(pB + 16 * BSTR + kt * 32);
    bf16x8 b2v = *(const bf16x8*)(pB + 32 * BSTR + kt * 32);
    bf16x8 b3v = *(const bf16x8*)(pB + 48 * BSTR + kt * 32);
    ac0 = __builtin_amdgcn_mfma_f32_16x16x32_bf16(a, b0,  ac0, 0, 0, 0);
    ac1 = __builtin_amdgcn_mfma_f32_16x16x32_bf16(a, b1v, ac1, 0, 0, 0);
    ac2 = __builtin_amdgcn_mfma_f32_16x16x32_bf16(a, b2v, ac2, 0, 0, 0);
    ac3 = __builtin_amdgcn_mfma_f32_16x16x32_bf16(a, b3v, ac3, 0, 0, 0);
  }
  const float bias0 = b2[nl], bias1 = b2[16 + nl],
              bias2 = b2[32 + nl], bias3 = b2[48 + nl];
#pragma unroll
  for (int r = 0; r < 4; ++r) {
    int node = base + w * 16 + q * 4 + r;
    if (node < n) {
      bf16* o = xout + (size_t)node * HID;
      o[nl]      = __float2bfloat16(ac0[r] + bias0);
      o[16 + nl] = __float2bfloat16(ac1[r] + bias1);
      o[32 + nl] = __float2bfloat16(ac2[r] + bias2);
      o[48 + nl] = __float2bfloat16(ac3[r] + bias3);
    }
  }
}

// ---------------- SpMM2 (quad-gather) + ReLU + Wout-dot -> block partial -----
__global__ __launch_bounds__(256) void spmm2_fused_kernel(
    const int* __restrict__ row_ptr, const int2* __restrict__ ce,
    const bf16* __restrict__ x, const float* __restrict__ Wout,
    float* __restrict__ partials, int n) {
  const int lane = threadIdx.x & 63;
  const int sub = lane >> 4;
  const int fl  = lane & 15;
  const int g = threadIdx.x >> 6;
  const int r = blockIdx.x * 4 + g;
  const ushort* xp = (const ushort*)x;
  float wpart = 0.f;
  if (r < n) {
    int i = row_ptr[r];
    const int end = row_ptr[r + 1];
    float4 acc = {0.f, 0.f, 0.f, 0.f};
    for (; i + 16 <= end; i += 16) {
      int2 m0 = ce[i],    m1 = ce[i+1],  m2 = ce[i+2],  m3 = ce[i+3];
      int2 m4 = ce[i+4],  m5 = ce[i+5],  m6 = ce[i+6],  m7 = ce[i+7];
      int2 m8 = ce[i+8],  m9 = ce[i+9],  ma = ce[i+10], mb = ce[i+11];
      int2 mc = ce[i+12], md = ce[i+13], me = ce[i+14], mf = ce[i+15];
      QUAD(m0, m1, m2, m3); QUAD(m4, m5, m6, m7);
      QUAD(m8, m9, ma, mb); QUAD(mc, md, me, mf);
    }
    for (; i < end; i += 8) {
      QUAD_TAIL(i);
      QUAD_TAIL(i + 4);
    }
    acc.x += __shfl_xor(acc.x, 16); acc.x += __shfl_xor(acc.x, 32);
    acc.y += __shfl_xor(acc.y, 16); acc.y += __shfl_xor(acc.y, 32);
    acc.z += __shfl_xor(acc.z, 16); acc.z += __shfl_xor(acc.z, 32);
    acc.w += __shfl_xor(acc.w, 16); acc.w += __shfl_xor(acc.w, 32);
    if (sub == 0) {
      const float4 wv = ((const float4*)Wout)[fl];
      wpart = fmaxf(acc.x, 0.f) * wv.x + fmaxf(acc.y, 0.f) * wv.y
            + fmaxf(acc.z, 0.f) * wv.z + fmaxf(acc.w, 0.f) * wv.w;
    }
  }
  for (int off = 32; off; off >>= 1) wpart += __shfl_down(wpart, off, 64);
  __shared__ float part[4];
  if (lane == 0) part[g] = wpart;
  __syncthreads();
  if (threadIdx.x == 0)
    partials[blockIdx.x] = part[0] + part[1] + part[2] + part[3];
}

// ---------------- final: sum 25k partials (1 block, float4) ------------------
__global__ __launch_bounds__(1024) void reduce_kernel(
    const float* __restrict__ partials, const float* __restrict__ bout,
    float* __restrict__ out, int m) {
  const int t = threadIdx.x;
  float s = 0.f;
  const int m4 = m >> 2;
  for (int i = t; i < m4; i += 1024) {
    float4 v = ((const float4*)partials)[i];
    s += v.x + v.y + v.z + v.w;
  }
  if (t < (m & 3)) s += partials[(m & ~3) + t];
  for (int off = 32; off; off >>= 1) s += __shfl_down(s, off, 64);
  __shared__ float wsum[16];
  if ((t & 63) == 0) wsum[t >> 6] = s;
  __syncthreads();
  if (t == 0) {
    float tot = bout[0];
    for (int w = 0; w < 16; ++w) tot += wsum[w];
    out[0] = tot;
  }
}

extern "C" void kernel_launch(void* const* d_in, const int* in_sizes, int n_in,
                              void* d_out, int out_size, void* d_ws, size_t ws_size,
                              hipStream_t stream) {
  const float* emb  = (const float*)d_in[0];
  const float* deg  = (const float*)d_in[1];
  const float* seed = (const float*)d_in[2];
  const int*   row  = (const int*)d_in[3];
  const int*   col  = (const int*)d_in[4];
  const float* vals = (const float*)d_in[5];
  const float* W1   = (const float*)d_in[6];
  const float* b1   = (const float*)d_in[7];
  const float* W2   = (const float*)d_in[8];
  const float* b2   = (const float*)d_in[9];
  const float* Wout = (const float*)d_in[10];
  const float* bout = (const float*)d_in[11];
  float* out = (float*)d_out;

  const int n  = in_sizes[0] / IN_EMB;   // 100000
  const int nE = in_sizes[3];            // 3200000
  const int nbkt = (n + ROWS_PER_BKT - 1) / ROWS_PER_BKT;   // 782

  const int lin_blocks  = (n + 63) / 64;
  const int row_blocks  = (n + 3) / 4;
  const int part_blocks = (nE + PART_CHUNK - 1) / PART_CHUNK;

  // ---- workspace layout ----
  char* ws = (char*)d_ws;
  int2* ce   = (int2*)ws;  ws += (size_t)nE * sizeof(int2);             // live to end
  char* tmpb = ws;
  int2* tmp  = (int2*)ws;  ws += (size_t)nE * sizeof(int2);             // dead after sort
  bf16* xa   = (bf16*)ws;  ws += ((size_t)n * HID * 2 + 255) & ~255ULL;
  bf16* xb   = (bf16*)ws;  ws += ((size_t)n * HID * 2 + 255) & ~255ULL;
  int* row_ptr = (int*)ws; ws += ((size_t)(n + 1) * 4 + 255) & ~255ULL;
  int* bcnt    = (int*)ws; ws += ((size_t)nbkt * 4 + 255) & ~255ULL;
  int* bstart  = (int*)ws; ws += ((size_t)(nbkt + 1) * 4 + 255) & ~255ULL;
  int* bcur    = (int*)ws; ws += ((size_t)nbkt * 4 + 255) & ~255ULL;
  float* partials = (float*)ws;                                         // row_blocks floats
  bf16* ya = (bf16*)tmpb;   // alias: tmp dead before spmm1 writes ya

  // ---- CSR build ----
  hipMemsetAsync(bcnt, 0, (size_t)nbkt * sizeof(int), stream);
  bhist_kernel<<<1024, 256, 0, stream>>>(row, bcnt, nE, nbkt);
  bscan_kernel<<<1, 1024, 0, stream>>>(bcnt, bstart, bcur, row_ptr, n, nbkt);
  partition_kernel<<<part_blocks, 512, 0, stream>>>(row, col, vals, bcur, tmp, nE);
  bucket_sort_kernel<<<nbkt, 512, 0, stream>>>(bstart, tmp, ce, row_ptr, n);

  // ---- network ----
  lin1_kernel<<<lin_blocks, 256, 0, stream>>>(emb, deg, seed, W1, b1, xa, n);
  spmm_csr_kernel<<<row_blocks, 256, 0, stream>>>(row_ptr, ce, xa, ya, n);
  lin2_kernel<<<lin_blocks, 256, 0, stream>>>(ya, W2, b2, xb, n);
  spmm2_fused_kernel<<<row_blocks, 256, 0, stream>>>(row_ptr, ce, xb, Wout, partials, n);
  reduce_kernel<<<1, 1024, 0, stream>>>(partials, bout, out, row_blocks);
}

// Round 9
// 450.774 us; speedup vs baseline: 1.8513x; 1.0123x over previous
//
#include <hip/hip_runtime.h>
#include <hip/hip_bf16.h>

#define HID 64
#define IN_EMB 128
#define IN_DIM 130
#define ROWS_PER_BKT 128
#define LOG_RPB 7
#define MAX_BKT 1024          // 100000/128 = 782 buckets actually used
#define PART_CHUNK 4096       // edges per partition block (782 blocks)
#define ASTR 168              // lin1 LDS row stride (shorts)
#define BSTR 72               // lin2 LDS row stride (shorts)

typedef __hip_bfloat16 bf16;
typedef __attribute__((ext_vector_type(8))) short bf16x8;
typedef __attribute__((ext_vector_type(4))) float fx4;

__device__ __forceinline__ float bf2f(unsigned short u) {
  return __uint_as_float((unsigned)u << 16);
}
__device__ __forceinline__ short f2bfs(float f) {
  __hip_bfloat16 h = __float2bfloat16(f);
  return *(reinterpret_cast<short*>(&h));
}

// ---------------- coarse histogram over row-buckets (int4 loads) -------------
__global__ __launch_bounds__(256) void bhist_kernel(const int* __restrict__ row,
                                                    int* __restrict__ bcnt,
                                                    int nE, int nbkt) {
  __shared__ int h[MAX_BKT];
  for (int i = threadIdx.x; i < MAX_BKT; i += 256) h[i] = 0;
  __syncthreads();
  const int tot4 = nE >> 2;
  const int stride = gridDim.x * 256;
  for (int idx = blockIdx.x * 256 + threadIdx.x; idx < tot4; idx += stride) {
    int4 r4 = ((const int4*)row)[idx];
    atomicAdd(&h[r4.x >> LOG_RPB], 1);
    atomicAdd(&h[r4.y >> LOG_RPB], 1);
    atomicAdd(&h[r4.z >> LOG_RPB], 1);
    atomicAdd(&h[r4.w >> LOG_RPB], 1);
  }
  if (blockIdx.x == 0 && threadIdx.x < (nE & 3))
    atomicAdd(&h[row[(nE & ~3) + threadIdx.x] >> LOG_RPB], 1);
  __syncthreads();
  for (int i = threadIdx.x; i < nbkt; i += 256)
    if (h[i]) atomicAdd(&bcnt[i], h[i]);
}

// ---------------- exclusive scan of bucket counts (1 block) ------------------
__global__ __launch_bounds__(1024) void bscan_kernel(const int* __restrict__ bcnt,
                                                     int* __restrict__ bstart,
                                                     int* __restrict__ bcur,
                                                     int* __restrict__ row_ptr,
                                                     int n, int nbkt) {
  __shared__ int s[1024];
  const int t = threadIdx.x;
  const int v = (t < nbkt) ? bcnt[t] : 0;
  s[t] = v;
  __syncthreads();
  for (int off = 1; off < 1024; off <<= 1) {
    int u = (t >= off) ? s[t - off] : 0;
    __syncthreads();
    s[t] += u;
    __syncthreads();
  }
  if (t < nbkt) { int ex = s[t] - v; bstart[t] = ex; bcur[t] = ex; }
  if (t == 0) { bstart[nbkt] = s[1023]; row_ptr[n] = s[1023]; }   // == nE
}

// ---------------- partition edges into row-buckets (vectorized, 512T) --------
// packed edge: .x = col | (local_row << 20), .y = bits(val)
__global__ __launch_bounds__(512) void partition_kernel(
    const int* __restrict__ row, const int* __restrict__ col,
    const float* __restrict__ vals, int* __restrict__ bcur,
    int2* __restrict__ tmp, int nE) {
  __shared__ int h[MAX_BKT];
  __shared__ int cur[MAX_BKT];
  const int t = threadIdx.x;
  const int base = blockIdx.x * PART_CHUNK;      // multiple of 4096
  for (int i = t; i < MAX_BKT; i += 512) h[i] = 0;
  __syncthreads();
  // phase A: local bucket histogram (int4)
  for (int kk = t; kk < PART_CHUNK / 4; kk += 512) {
    int e0 = base + kk * 4;
    if (e0 + 3 < nE) {
      int4 r4 = ((const int4*)row)[(base >> 2) + kk];
      atomicAdd(&h[r4.x >> LOG_RPB], 1);
      atomicAdd(&h[r4.y >> LOG_RPB], 1);
      atomicAdd(&h[r4.z >> LOG_RPB], 1);
      atomicAdd(&h[r4.w >> LOG_RPB], 1);
    } else {
      for (int j = 0; j < 4; ++j) {
        int e = e0 + j;
        if (e < nE) atomicAdd(&h[row[e] >> LOG_RPB], 1);
      }
    }
  }
  __syncthreads();
  // phase B: reserve contiguous runs
  for (int b = t; b < MAX_BKT; b += 512)
    if (h[b] > 0) cur[b] = atomicAdd(&bcur[b], h[b]);
  __syncthreads();
  // phase C: re-read, write grouped
  for (int kk = t; kk < PART_CHUNK / 4; kk += 512) {
    int e0 = base + kk * 4;
    if (e0 + 3 < nE) {
      int4 r4 = ((const int4*)row)[(base >> 2) + kk];
      int4 c4 = ((const int4*)col)[(base >> 2) + kk];
      float4 v4 = ((const float4*)vals)[(base >> 2) + kk];
      int rr[4] = {r4.x, r4.y, r4.z, r4.w};
      int cc[4] = {c4.x, c4.y, c4.z, c4.w};
      float vv[4] = {v4.x, v4.y, v4.z, v4.w};
#pragma unroll
      for (int j = 0; j < 4; ++j) {
        int b = rr[j] >> LOG_RPB;
        int p = atomicAdd(&cur[b], 1);
        tmp[p] = make_int2(cc[j] | ((rr[j] & (ROWS_PER_BKT - 1)) << 20),
                           __float_as_int(vv[j]));
      }
    } else {
      for (int j = 0; j < 4; ++j) {
        int e = e0 + j;
        if (e < nE) {
          int r = row[e];
          int b = r >> LOG_RPB;
          int p = atomicAdd(&cur[b], 1);
          tmp[p] = make_int2(col[e] | ((r & (ROWS_PER_BKT - 1)) << 20),
                             __float_as_int(vals[e]));
        }
      }
    }
  }
}

// ---------------- per-bucket counting sort -> exact CSR + row_ptr (512T) -----
__global__ __launch_bounds__(512) void bucket_sort_kernel(
    const int* __restrict__ bstart, const int2* __restrict__ tmp,
    int2* __restrict__ ce, int* __restrict__ row_ptr, int n) {
  __shared__ int rcnt[ROWS_PER_BKT];
  __shared__ int rpos[ROWS_PER_BKT];
  __shared__ int sc[ROWS_PER_BKT];
  const int t = threadIdx.x;
  const int b = blockIdx.x;
  const int start = bstart[b];
  const int end   = bstart[b + 1];
  if (t < ROWS_PER_BKT) rcnt[t] = 0;
  __syncthreads();
  for (int i = start + t; i < end; i += 512)
    atomicAdd(&rcnt[tmp[i].x >> 20], 1);
  __syncthreads();
  if (t < ROWS_PER_BKT) sc[t] = rcnt[t];
  __syncthreads();
  for (int off = 1; off < ROWS_PER_BKT; off <<= 1) {
    int u = (t < ROWS_PER_BKT && t >= off) ? sc[t - off] : 0;
    __syncthreads();
    if (t < ROWS_PER_BKT) sc[t] += u;
    __syncthreads();
  }
  if (t < ROWS_PER_BKT) {
    int ex = sc[t] - rcnt[t];
    int gpos = start + ex;
    rpos[t] = gpos;
    int gr = b * ROWS_PER_BKT + t;
    if (gr < n) row_ptr[gr] = gpos;
  }
  __syncthreads();
  for (int i = start + t; i < end; i += 512) {
    int2 e = tmp[i];
    int p = atomicAdd(&rpos[e.x >> 20], 1);
    ce[p] = make_int2(e.x & 0xFFFFF, e.y);
  }
}

// ---------------- Linear1 via MFMA -------------------------------------------
__global__ __launch_bounds__(256) void lin1_kernel(
    const float* __restrict__ emb, const float* __restrict__ deg,
    const float* __restrict__ seed, const float* __restrict__ W1,
    const float* __restrict__ b1, bf16* __restrict__ out, int n) {
  __shared__ short sA[64 * ASTR];
  __shared__ short sB[64 * ASTR];
  const int t = threadIdx.x;
  const int base = blockIdx.x * 64;

  for (int idx = t; idx < 64 * 160; idx += 256) {
    int k = idx >> 6, nn = idx & 63;
    float v = (k < IN_DIM) ? W1[k * HID + nn] : 0.f;
    sB[nn * ASTR + k] = f2bfs(v);
  }
  for (int idx = t; idx < 64 * 32; idx += 256) {
    int nn = idx >> 5, k4 = idx & 31;
    int node = base + nn;
    short4 w;
    if (node < n) {
      float4 v = ((const float4*)emb)[(size_t)node * 32 + k4];
      w = make_short4(f2bfs(v.x), f2bfs(v.y), f2bfs(v.z), f2bfs(v.w));
    } else {
      w = make_short4(0, 0, 0, 0);
    }
    *(short4*)&sA[nn * ASTR + 4 * k4] = w;
  }
  for (int idx = t; idx < 64 * 32; idx += 256) {
    int nn = idx >> 5, kk = idx & 31;
    int node = base + nn;
    float v = 0.f;
    if (node < n) {
      if (kk == 0) v = deg[node];
      else if (kk == 1) v = seed[node];
    }
    sA[nn * ASTR + 128 + kk] = f2bfs(v);
  }
  __syncthreads();

  const int lane = t & 63, w = t >> 6;
  const int nl = lane & 15, q = lane >> 4;
  const short* pA = &sA[(w * 16 + nl) * ASTR + q * 8];
  const short* pB = &sB[nl * ASTR + q * 8];
  fx4 ac0 = {0.f, 0.f, 0.f, 0.f}, ac1 = ac0, ac2 = ac0, ac3 = ac0;
#pragma unroll
  for (int kt = 0; kt < 5; ++kt) {
    bf16x8 a   = *(const bf16x8*)(pA + kt * 32);
    bf16x8 b0  = *(const bf16x8*)(pB + kt * 32);
    bf16x8 b1v = *(const bf16x8*)(pB + 16 * ASTR + kt * 32);
    bf16x8 b2v = *(const bf16x8*)(pB + 32 * ASTR + kt * 32);
    bf16x8 b3v = *(const bf16x8*)(pB + 48 * ASTR + kt * 32);
    ac0 = __builtin_amdgcn_mfma_f32_16x16x32_bf16(a, b0,  ac0, 0, 0, 0);
    ac1 = __builtin_amdgcn_mfma_f32_16x16x32_bf16(a, b1v, ac1, 0, 0, 0);
    ac2 = __builtin_amdgcn_mfma_f32_16x16x32_bf16(a, b2v, ac2, 0, 0, 0);
    ac3 = __builtin_amdgcn_mfma_f32_16x16x32_bf16(a, b3v, ac3, 0, 0, 0);
  }
  const float bias0 = b1[nl], bias1 = b1[16 + nl],
              bias2 = b1[32 + nl], bias3 = b1[48 + nl];
#pragma unroll
  for (int r = 0; r < 4; ++r) {
    int node = base + w * 16 + q * 4 + r;
    if (node < n) {
      bf16* o = out + (size_t)node * HID;
      o[nl]      = __float2bfloat16(ac0[r] + bias0);
      o[16 + nl] = __float2bfloat16(ac1[r] + bias1);
      o[32 + nl] = __float2bfloat16(ac2[r] + bias2);
      o[48 + nl] = __float2bfloat16(ac3[r] + bias3);
    }
  }
}

// ---- quad-gather v2: each 16-lane sub loads ITS edge directly (1 vmem), -----
// ---- nontemporal ce stream (don't evict x from L2) --------------------------
#define GQ(ev)                                                                \
  {                                                                           \
    const float v = __int_as_float((int)((ev) >> 32));                        \
    const int   c = (int)((ev) & 0xFFFFFu);                                   \
    const ushort4 u = *(const ushort4*)(xp + ((size_t)c << 6) + 4 * fl);      \
    acc.x += v * bf2f(u.x); acc.y += v * bf2f(u.y);                           \
    acc.z += v * bf2f(u.z); acc.w += v * bf2f(u.w);                           \
  }

#define GQ_TAIL(i0)                                                           \
  {                                                                           \
    int ei = (i0) + sub;                                                      \
    bool ok = ei < end;                                                       \
    int2 e = ce[ok ? ei : end - 1];                                           \
    float v = ok ? __int_as_float(e.y) : 0.f;                                 \
    const ushort4 u = *(const ushort4*)(xp + ((size_t)e.x << 6) + 4 * fl);    \
    acc.x += v * bf2f(u.x); acc.y += v * bf2f(u.y);                           \
    acc.z += v * bf2f(u.z); acc.w += v * bf2f(u.w);                           \
  }

// ---------------- SpMM1 (exact CSR, quad-gather v2) + fused ReLU -------------
__global__ __launch_bounds__(256) void spmm_csr_kernel(
    const int* __restrict__ row_ptr, const int2* __restrict__ ce,
    const bf16* __restrict__ x, bf16* __restrict__ y, int n) {
  const int lane = threadIdx.x & 63;
  const int sub = lane >> 4;
  const int fl  = lane & 15;
  const int r = blockIdx.x * 4 + (threadIdx.x >> 6);
  if (r >= n) return;
  const ushort* xp = (const ushort*)x;
  const unsigned long long* cep = (const unsigned long long*)ce;
  int i = row_ptr[r];
  const int end = row_ptr[r + 1];
  float4 acc = {0.f, 0.f, 0.f, 0.f};
  for (; i + 16 <= end; i += 16) {
    unsigned long long ea = __builtin_nontemporal_load(cep + i + sub);
    unsigned long long eb = __builtin_nontemporal_load(cep + i + 4 + sub);
    unsigned long long ec = __builtin_nontemporal_load(cep + i + 8 + sub);
    unsigned long long ed = __builtin_nontemporal_load(cep + i + 12 + sub);
    GQ(ea); GQ(eb); GQ(ec); GQ(ed);
  }
  for (; i < end; i += 8) {    // clamped tail, 2 sub-quads per iter
    GQ_TAIL(i);
    GQ_TAIL(i + 4);
  }
  acc.x += __shfl_xor(acc.x, 16); acc.x += __shfl_xor(acc.x, 32);
  acc.y += __shfl_xor(acc.y, 16); acc.y += __shfl_xor(acc.y, 32);
  acc.z += __shfl_xor(acc.z, 16); acc.z += __shfl_xor(acc.z, 32);
  acc.w += __shfl_xor(acc.w, 16); acc.w += __shfl_xor(acc.w, 32);
  if (sub == 0) {
    short4 o = make_short4(f2bfs(fmaxf(acc.x, 0.f)), f2bfs(fmaxf(acc.y, 0.f)),
                           f2bfs(fmaxf(acc.z, 0.f)), f2bfs(fmaxf(acc.w, 0.f)));
    *(short4*)((short*)y + ((size_t)r << 6) + 4 * fl) = o;
  }
}

// ---------------- Linear2 via MFMA (A from global) ---------------------------
__global__ __launch_bounds__(256) void lin2_kernel(
    const bf16* __restrict__ yin, const float* __restrict__ W2,
    const float* __restrict__ b2, bf16* __restrict__ xout, int n) {
  __shared__ short sB[64 * BSTR];
  const int t = threadIdx.x;
  const int base = blockIdx.x * 64;
  for (int idx = t; idx < 64 * 64; idx += 256) {
    int k = idx >> 6, nn = idx & 63;
    sB[nn * BSTR + k] = f2bfs(W2[k * HID + nn]);
  }
  __syncthreads();

  const int lane = t & 63, w = t >> 6;
  const int nl = lane & 15, q = lane >> 4;
  const short* xg = (const short*)yin + ((size_t)(base + w * 16 + nl)) * HID + q * 8;
  const short* pB = &sB[nl * BSTR + q * 8];
  fx4 ac0 = {0.f, 0.f, 0.f, 0.f}, ac1 = ac0, ac2 = ac0, ac3 = ac0;
#pragma unroll
  for (int kt = 0; kt < 2; ++kt) {
    bf16x8 a   = *(const bf16x8*)(xg + kt * 32);
    bf16x8 b0  = *(const bf16x8*)(pB + kt * 32);
    bf16x8 b1v = *(const bf16x8*)(pB + 16 * BSTR + kt * 32);
    bf16x8 b2v = *(const bf16x8*)(pB + 32 * BSTR + kt * 32);
    bf16x8 b3v = *(const bf16x8*)(pB + 48 * BSTR + kt * 32);
    ac0 = __builtin_amdgcn_mfma_f32_16x16x32_bf16(a, b0,  ac0, 0, 0, 0);
    ac1 = __builtin_amdgcn_mfma_f32_16x16x32_bf16(a, b1v, ac1, 0, 0, 0);
    ac2 = __builtin_amdgcn_mfma_f32_16x16x32_bf16(a, b2v, ac2, 0, 0, 0);
    ac3 = __builtin_amdgcn_mfma_f32_16x16x32_bf16(a, b3v, ac3, 0, 0, 0);
  }
  const float bias0 = b2[nl], bias1 = b2[16 + nl],
              bias2 = b2[32 + nl], bias3 = b2[48 + nl];
#pragma unroll
  for (int r = 0; r < 4; ++r) {
    int node = base + w * 16 + q * 4 + r;
    if (node < n) {
      bf16* o = xout + (size_t)node * HID;
      o[nl]      = __float2bfloat16(ac0[r] + bias0);
      o[16 + nl] = __float2bfloat16(ac1[r] + bias1);
      o[32 + nl] = __float2bfloat16(ac2[r] + bias2);
      o[48 + nl] = __float2bfloat16(ac3[r] + bias3);
    }
  }
}

// ---------------- SpMM2 (quad-gather v2) + ReLU + Wout-dot -> block partial --
__global__ __launch_bounds__(256) void spmm2_fused_kernel(
    const int* __restrict__ row_ptr, const int2* __restrict__ ce,
    const bf16* __restrict__ x, const float* __restrict__ Wout,
    float* __restrict__ partials, int n) {
  const int lane = threadIdx.x & 63;
  const int sub = lane >> 4;
  const int fl  = lane & 15;
  const int g = threadIdx.x >> 6;
  const int r = blockIdx.x * 4 + g;
  const ushort* xp = (const ushort*)x;
  const unsigned long long* cep = (const unsigned long long*)ce;
  float wpart = 0.f;
  if (r < n) {
    int i = row_ptr[r];
    const int end = row_ptr[r + 1];
    float4 acc = {0.f, 0.f, 0.f, 0.f};
    for (; i + 16 <= end; i += 16) {
      unsigned long long ea = __builtin_nontemporal_load(cep + i + sub);
      unsigned long long eb = __builtin_nontemporal_load(cep + i + 4 + sub);
      unsigned long long ec = __builtin_nontemporal_load(cep + i + 8 + sub);
      unsigned long long ed = __builtin_nontemporal_load(cep + i + 12 + sub);
      GQ(ea); GQ(eb); GQ(ec); GQ(ed);
    }
    for (; i < end; i += 8) {
      GQ_TAIL(i);
      GQ_TAIL(i + 4);
    }
    acc.x += __shfl_xor(acc.x, 16); acc.x += __shfl_xor(acc.x, 32);
    acc.y += __shfl_xor(acc.y, 16); acc.y += __shfl_xor(acc.y, 32);
    acc.z += __shfl_xor(acc.z, 16); acc.z += __shfl_xor(acc.z, 32);
    acc.w += __shfl_xor(acc.w, 16); acc.w += __shfl_xor(acc.w, 32);
    if (sub == 0) {
      const float4 wv = ((const float4*)Wout)[fl];
      wpart = fmaxf(acc.x, 0.f) * wv.x + fmaxf(acc.y, 0.f) * wv.y
            + fmaxf(acc.z, 0.f) * wv.z + fmaxf(acc.w, 0.f) * wv.w;
    }
  }
  for (int off = 32; off; off >>= 1) wpart += __shfl_down(wpart, off, 64);
  __shared__ float part[4];
  if (lane == 0) part[g] = wpart;
  __syncthreads();
  if (threadIdx.x == 0)
    partials[blockIdx.x] = part[0] + part[1] + part[2] + part[3];
}

// ---------------- final: sum 25k partials (1 block, float4) ------------------
__global__ __launch_bounds__(1024) void reduce_kernel(
    const float* __restrict__ partials, const float* __restrict__ bout,
    float* __restrict__ out, int m) {
  const int t = threadIdx.x;
  float s = 0.f;
  const int m4 = m >> 2;
  for (int i = t; i < m4; i += 1024) {
    float4 v = ((const float4*)partials)[i];
    s += v.x + v.y + v.z + v.w;
  }
  if (t < (m & 3)) s += partials[(m & ~3) + t];
  for (int off = 32; off; off >>= 1) s += __shfl_down(s, off, 64);
  __shared__ float wsum[16];
  if ((t & 63) == 0) wsum[t >> 6] = s;
  __syncthreads();
  if (t == 0) {
    float tot = bout[0];
    for (int w = 0; w < 16; ++w) tot += wsum[w];
    out[0] = tot;
  }
}

extern "C" void kernel_launch(void* const* d_in, const int* in_sizes, int n_in,
                              void* d_out, int out_size, void* d_ws, size_t ws_size,
                              hipStream_t stream) {
  const float* emb  = (const float*)d_in[0];
  const float* deg  = (const float*)d_in[1];
  const float* seed = (const float*)d_in[2];
  const int*   row  = (const int*)d_in[3];
  const int*   col  = (const int*)d_in[4];
  const float* vals = (const float*)d_in[5];
  const float* W1   = (const float*)d_in[6];
  const float* b1   = (const float*)d_in[7];
  const float* W2   = (const float*)d_in[8];
  const float* b2   = (const float*)d_in[9];
  const float* Wout = (const float*)d_in[10];
  const float* bout = (const float*)d_in[11];
  float* out = (float*)d_out;

  const int n  = in_sizes[0] / IN_EMB;   // 100000
  const int nE = in_sizes[3];            // 3200000
  const int nbkt = (n + ROWS_PER_BKT - 1) / ROWS_PER_BKT;   // 782

  const int lin_blocks  = (n + 63) / 64;
  const int row_blocks  = (n + 3) / 4;
  const int part_blocks = (nE + PART_CHUNK - 1) / PART_CHUNK;

  // ---- workspace layout ----
  char* ws = (char*)d_ws;
  int2* ce   = (int2*)ws;  ws += (size_t)nE * sizeof(int2);             // live to end
  char* tmpb = ws;
  int2* tmp  = (int2*)ws;  ws += (size_t)nE * sizeof(int2);             // dead after sort
  bf16* xa   = (bf16*)ws;  ws += ((size_t)n * HID * 2 + 255) & ~255ULL;
  bf16* xb   = (bf16*)ws;  ws += ((size_t)n * HID * 2 + 255) & ~255ULL;
  int* row_ptr = (int*)ws; ws += ((size_t)(n + 1) * 4 + 255) & ~255ULL;
  int* bcnt    = (int*)ws; ws += ((size_t)nbkt * 4 + 255) & ~255ULL;
  int* bstart  = (int*)ws; ws += ((size_t)(nbkt + 1) * 4 + 255) & ~255ULL;
  int* bcur    = (int*)ws; ws += ((size_t)nbkt * 4 + 255) & ~255ULL;
  float* partials = (float*)ws;                                         // row_blocks floats
  bf16* ya = (bf16*)tmpb;   // alias: tmp dead before spmm1 writes ya

  // ---- CSR build ----
  hipMemsetAsync(bcnt, 0, (size_t)nbkt * sizeof(int), stream);
  bhist_kernel<<<1024, 256, 0, stream>>>(row, bcnt, nE, nbkt);
  bscan_kernel<<<1, 1024, 0, stream>>>(bcnt, bstart, bcur, row_ptr, n, nbkt);
  partition_kernel<<<part_blocks, 512, 0, stream>>>(row, col, vals, bcur, tmp, nE);
  bucket_sort_kernel<<<nbkt, 512, 0, stream>>>(bstart, tmp, ce, row_ptr, n);

  // ---- network ----
  lin1_kernel<<<lin_blocks, 256, 0, stream>>>(emb, deg, seed, W1, b1, xa, n);
  spmm_csr_kernel<<<row_blocks, 256, 0, stream>>>(row_ptr, ce, xa, ya, n);
  lin2_kernel<<<lin_blocks, 256, 0, stream>>>(ya, W2, b2, xb, n);
  spmm2_fused_kernel<<<row_blocks, 256, 0, stream>>>(row_ptr, ce, xb, Wout, partials, n);
  reduce_kernel<<<1, 1024, 0, stream>>>(partials, bout, out, row_blocks);
}

// Round 10
// 417.953 us; speedup vs baseline: 1.9967x; 1.0785x over previous
//
#include <hip/hip_runtime.h>
#include <hip/hip_bf16.h>

#define HID 64
#define IN_EMB 128
#define IN_DIM 130
#define ROWS_PER_BKT 128
#define LOG_RPB 7
#define MAX_BKT 1024          // 100000/128 = 782 buckets actually used
#define PART_CHUNK 4096       // edges per partition block (782 blocks)
#define ASTR 168              // lin1 LDS row stride (shorts)
#define BSTR 72               // lin2 LDS row stride (shorts)
#define SORT_CAP 6144         // bucket_sort LDS capacity (edges); run avg 4094, max ~4400

typedef __hip_bfloat16 bf16;
typedef __attribute__((ext_vector_type(8))) short bf16x8;
typedef __attribute__((ext_vector_type(4))) float fx4;
typedef __attribute__((ext_vector_type(2))) float fx2;

__device__ __forceinline__ short f2bfs(float f) {
  __hip_bfloat16 h = __float2bfloat16(f);
  return *(reinterpret_cast<short*>(&h));
}
// pack 4 floats -> 4 fp8 e4m3 bytes (HW cvt)
__device__ __forceinline__ int pk_fp8x4(float a, float b, float c, float d) {
  int v = __builtin_amdgcn_cvt_pk_fp8_f32(a, b, 0, false);
  v = __builtin_amdgcn_cvt_pk_fp8_f32(c, d, v, true);
  return v;
}
__device__ __forceinline__ unsigned char f2fp8(float x) {
  return (unsigned char)(__builtin_amdgcn_cvt_pk_fp8_f32(x, x, 0, false) & 0xFF);
}

// ---------------- coarse histogram over row-buckets (int4 loads) -------------
__global__ __launch_bounds__(256) void bhist_kernel(const int* __restrict__ row,
                                                    int* __restrict__ bcnt,
                                                    int nE, int nbkt) {
  __shared__ int h[MAX_BKT];
  for (int i = threadIdx.x; i < MAX_BKT; i += 256) h[i] = 0;
  __syncthreads();
  const int tot4 = nE >> 2;
  const int stride = gridDim.x * 256;
  for (int idx = blockIdx.x * 256 + threadIdx.x; idx < tot4; idx += stride) {
    int4 r4 = ((const int4*)row)[idx];
    atomicAdd(&h[r4.x >> LOG_RPB], 1);
    atomicAdd(&h[r4.y >> LOG_RPB], 1);
    atomicAdd(&h[r4.z >> LOG_RPB], 1);
    atomicAdd(&h[r4.w >> LOG_RPB], 1);
  }
  if (blockIdx.x == 0 && threadIdx.x < (nE & 3))
    atomicAdd(&h[row[(nE & ~3) + threadIdx.x] >> LOG_RPB], 1);
  __syncthreads();
  for (int i = threadIdx.x; i < nbkt; i += 256)
    if (h[i]) atomicAdd(&bcnt[i], h[i]);
}

// ---------------- exclusive scan of bucket counts (1 block) ------------------
__global__ __launch_bounds__(1024) void bscan_kernel(const int* __restrict__ bcnt,
                                                     int* __restrict__ bstart,
                                                     int* __restrict__ bcur,
                                                     int* __restrict__ row_ptr,
                                                     int n, int nbkt) {
  __shared__ int s[1024];
  const int t = threadIdx.x;
  const int v = (t < nbkt) ? bcnt[t] : 0;
  s[t] = v;
  __syncthreads();
  for (int off = 1; off < 1024; off <<= 1) {
    int u = (t >= off) ? s[t - off] : 0;
    __syncthreads();
    s[t] += u;
    __syncthreads();
  }
  if (t < nbkt) { int ex = s[t] - v; bstart[t] = ex; bcur[t] = ex; }
  if (t == 0) { bstart[nbkt] = s[1023]; row_ptr[n] = s[1023]; }   // == nE
}

// ---------------- partition edges into row-buckets (vectorized, 512T) --------
// packed edge: .x = col | (local_row << 20), .y = bits(val)
__global__ __launch_bounds__(512) void partition_kernel(
    const int* __restrict__ row, const int* __restrict__ col,
    const float* __restrict__ vals, int* __restrict__ bcur,
    int2* __restrict__ tmp, int nE) {
  __shared__ int h[MAX_BKT];
  __shared__ int cur[MAX_BKT];
  const int t = threadIdx.x;
  const int base = blockIdx.x * PART_CHUNK;      // multiple of 4096
  for (int i = t; i < MAX_BKT; i += 512) h[i] = 0;
  __syncthreads();
  for (int kk = t; kk < PART_CHUNK / 4; kk += 512) {
    int e0 = base + kk * 4;
    if (e0 + 3 < nE) {
      int4 r4 = ((const int4*)row)[(base >> 2) + kk];
      atomicAdd(&h[r4.x >> LOG_RPB], 1);
      atomicAdd(&h[r4.y >> LOG_RPB], 1);
      atomicAdd(&h[r4.z >> LOG_RPB], 1);
      atomicAdd(&h[r4.w >> LOG_RPB], 1);
    } else {
      for (int j = 0; j < 4; ++j) {
        int e = e0 + j;
        if (e < nE) atomicAdd(&h[row[e] >> LOG_RPB], 1);
      }
    }
  }
  __syncthreads();
  for (int b = t; b < MAX_BKT; b += 512)
    if (h[b] > 0) cur[b] = atomicAdd(&bcur[b], h[b]);
  __syncthreads();
  for (int kk = t; kk < PART_CHUNK / 4; kk += 512) {
    int e0 = base + kk * 4;
    if (e0 + 3 < nE) {
      int4 r4 = ((const int4*)row)[(base >> 2) + kk];
      int4 c4 = ((const int4*)col)[(base >> 2) + kk];
      float4 v4 = ((const float4*)vals)[(base >> 2) + kk];
      int rr[4] = {r4.x, r4.y, r4.z, r4.w};
      int cc[4] = {c4.x, c4.y, c4.z, c4.w};
      float vv[4] = {v4.x, v4.y, v4.z, v4.w};
#pragma unroll
      for (int j = 0; j < 4; ++j) {
        int b = rr[j] >> LOG_RPB;
        int p = atomicAdd(&cur[b], 1);
        tmp[p] = make_int2(cc[j] | ((rr[j] & (ROWS_PER_BKT - 1)) << 20),
                           __float_as_int(vv[j]));
      }
    } else {
      for (int j = 0; j < 4; ++j) {
        int e = e0 + j;
        if (e < nE) {
          int r = row[e];
          int b = r >> LOG_RPB;
          int p = atomicAdd(&cur[b], 1);
          tmp[p] = make_int2(col[e] | ((r & (ROWS_PER_BKT - 1)) << 20),
                             __float_as_int(vals[e]));
        }
      }
    }
  }
}

// ---------------- per-bucket counting sort (LDS-staged run) ------------------
__global__ __launch_bounds__(512) void bucket_sort_kernel(
    const int* __restrict__ bstart, const int2* __restrict__ tmp,
    int2* __restrict__ ce, int* __restrict__ row_ptr, int n) {
  __shared__ int2 buf[SORT_CAP];            // 48 KB
  __shared__ int rcnt[ROWS_PER_BKT];
  __shared__ int rpos[ROWS_PER_BKT];
  __shared__ int sc[ROWS_PER_BKT];
  const int t = threadIdx.x;
  const int b = blockIdx.x;
  const int start = bstart[b];
  const int end   = bstart[b + 1];
  const int len = end - start;
  const int cap = len < SORT_CAP ? len : SORT_CAP;
  for (int i = t; i < cap; i += 512) buf[i] = tmp[start + i];
  if (t < ROWS_PER_BKT) rcnt[t] = 0;
  __syncthreads();
  for (int i = t; i < cap; i += 512)
    atomicAdd(&rcnt[buf[i].x >> 20], 1);
  for (int i = cap + t; i < len; i += 512)               // overflow (rare)
    atomicAdd(&rcnt[tmp[start + i].x >> 20], 1);
  __syncthreads();
  if (t < ROWS_PER_BKT) sc[t] = rcnt[t];
  __syncthreads();
  for (int off = 1; off < ROWS_PER_BKT; off <<= 1) {
    int u = (t < ROWS_PER_BKT && t >= off) ? sc[t - off] : 0;
    __syncthreads();
    if (t < ROWS_PER_BKT) sc[t] += u;
    __syncthreads();
  }
  if (t < ROWS_PER_BKT) {
    int ex = sc[t] - rcnt[t];
    int gpos = start + ex;
    rpos[t] = gpos;
    int gr = b * ROWS_PER_BKT + t;
    if (gr < n) row_ptr[gr] = gpos;
  }
  __syncthreads();
  for (int i = t; i < cap; i += 512) {
    int2 e = buf[i];
    int p = atomicAdd(&rpos[e.x >> 20], 1);
    ce[p] = make_int2(e.x & 0xFFFFF, e.y);
  }
  for (int i = cap + t; i < len; i += 512) {             // overflow (rare)
    int2 e = tmp[start + i];
    int p = atomicAdd(&rpos[e.x >> 20], 1);
    ce[p] = make_int2(e.x & 0xFFFFF, e.y);
  }
}

// ---------------- Linear1 via MFMA, fp8 activations out ----------------------
__global__ __launch_bounds__(256) void lin1_kernel(
    const float* __restrict__ emb, const float* __restrict__ deg,
    const float* __restrict__ seed, const float* __restrict__ W1,
    const float* __restrict__ b1, unsigned char* __restrict__ out, int n) {
  __shared__ short sA[64 * ASTR];
  __shared__ short sB[64 * ASTR];
  const int t = threadIdx.x;
  const int base = blockIdx.x * 64;

  for (int idx = t; idx < 64 * 160; idx += 256) {
    int k = idx >> 6, nn = idx & 63;
    float v = (k < IN_DIM) ? W1[k * HID + nn] : 0.f;
    sB[nn * ASTR + k] = f2bfs(v);
  }
  for (int idx = t; idx < 64 * 32; idx += 256) {
    int nn = idx >> 5, k4 = idx & 31;
    int node = base + nn;
    short4 w;
    if (node < n) {
      float4 v = ((const float4*)emb)[(size_t)node * 32 + k4];
      w = make_short4(f2bfs(v.x), f2bfs(v.y), f2bfs(v.z), f2bfs(v.w));
    } else {
      w = make_short4(0, 0, 0, 0);
    }
    *(short4*)&sA[nn * ASTR + 4 * k4] = w;
  }
  for (int idx = t; idx < 64 * 32; idx += 256) {
    int nn = idx >> 5, kk = idx & 31;
    int node = base + nn;
    float v = 0.f;
    if (node < n) {
      if (kk == 0) v = deg[node];
      else if (kk == 1) v = seed[node];
    }
    sA[nn * ASTR + 128 + kk] = f2bfs(v);
  }
  __syncthreads();

  const int lane = t & 63, w = t >> 6;
  const int nl = lane & 15, q = lane >> 4;
  const short* pA = &sA[(w * 16 + nl) * ASTR + q * 8];
  const short* pB = &sB[nl * ASTR + q * 8];
  fx4 ac0 = {0.f, 0.f, 0.f, 0.f}, ac1 = ac0, ac2 = ac0, ac3 = ac0;
#pragma unroll
  for (int kt = 0; kt < 5; ++kt) {
    bf16x8 a   = *(const bf16x8*)(pA + kt * 32);
    bf16x8 b0  = *(const bf16x8*)(pB + kt * 32);
    bf16x8 b1v = *(const bf16x8*)(pB + 16 * ASTR + kt * 32);
    bf16x8 b2v = *(const bf16x8*)(pB + 32 * ASTR + kt * 32);
    bf16x8 b3v = *(const bf16x8*)(pB + 48 * ASTR + kt * 32);
    ac0 = __builtin_amdgcn_mfma_f32_16x16x32_bf16(a, b0,  ac0, 0, 0, 0);
    ac1 = __builtin_amdgcn_mfma_f32_16x16x32_bf16(a, b1v, ac1, 0, 0, 0);
    ac2 = __builtin_amdgcn_mfma_f32_16x16x32_bf16(a, b2v, ac2, 0, 0, 0);
    ac3 = __builtin_amdgcn_mfma_f32_16x16x32_bf16(a, b3v, ac3, 0, 0, 0);
  }
  const float bias0 = b1[nl], bias1 = b1[16 + nl],
              bias2 = b1[32 + nl], bias3 = b1[48 + nl];
#pragma unroll
  for (int r = 0; r < 4; ++r) {
    int node = base + w * 16 + q * 4 + r;
    if (node < n) {
      unsigned char* o = out + ((size_t)node << 6);
      o[nl]      = f2fp8(ac0[r] + bias0);
      o[16 + nl] = f2fp8(ac1[r] + bias1);
      o[32 + nl] = f2fp8(ac2[r] + bias2);
      o[48 + nl] = f2fp8(ac3[r] + bias3);
    }
  }
}

// ---- fp8 quad-gather: each 16-lane sub loads its edge; uchar4 (4 feat)/lane -
#define GQ(ev)                                                                \
  {                                                                           \
    const float v = __int_as_float((int)((ev) >> 32));                        \
    const int   c = (int)((ev) & 0xFFFFFu);                                   \
    const unsigned u = *(const unsigned*)(xp + ((size_t)c << 6) + 4 * fl);    \
    fx2 p01 = __builtin_amdgcn_cvt_pk_f32_fp8(u, false);                      \
    fx2 p23 = __builtin_amdgcn_cvt_pk_f32_fp8(u, true);                       \
    acc.x += v * p01.x; acc.y += v * p01.y;                                   \
    acc.z += v * p23.x; acc.w += v * p23.y;                                   \
  }

#define GQ_TAIL(i0)                                                           \
  {                                                                           \
    int ei = (i0) + sub;                                                      \
    bool ok = ei < end;                                                       \
    int2 e = ce[ok ? ei : end - 1];                                           \
    float v = ok ? __int_as_float(e.y) : 0.f;                                 \
    const unsigned u = *(const unsigned*)(xp + ((size_t)e.x << 6) + 4 * fl);  \
    fx2 p01 = __builtin_amdgcn_cvt_pk_f32_fp8(u, false);                      \
    fx2 p23 = __builtin_amdgcn_cvt_pk_f32_fp8(u, true);                       \
    acc.x += v * p01.x; acc.y += v * p01.y;                                   \
    acc.z += v * p23.x; acc.w += v * p23.y;                                   \
  }

// ---------------- SpMM1 (exact CSR, fp8 gather) + fused ReLU -----------------
__global__ __launch_bounds__(256) void spmm_csr_kernel(
    const int* __restrict__ row_ptr, const int2* __restrict__ ce,
    const unsigned char* __restrict__ x, unsigned char* __restrict__ y, int n) {
  const int lane = threadIdx.x & 63;
  const int sub = lane >> 4;
  const int fl  = lane & 15;
  const int r = blockIdx.x * 4 + (threadIdx.x >> 6);
  if (r >= n) return;
  const unsigned char* xp = x;
  const unsigned long long* cep = (const unsigned long long*)ce;
  int i = row_ptr[r];
  const int end = row_ptr[r + 1];
  float4 acc = {0.f, 0.f, 0.f, 0.f};
  for (; i + 16 <= end; i += 16) {
    unsigned long long ea = __builtin_nontemporal_load(cep + i + sub);
    unsigned long long eb = __builtin_nontemporal_load(cep + i + 4 + sub);
    unsigned long long ec = __builtin_nontemporal_load(cep + i + 8 + sub);
    unsigned long long ed = __builtin_nontemporal_load(cep + i + 12 + sub);
    GQ(ea); GQ(eb); GQ(ec); GQ(ed);
  }
  for (; i < end; i += 8) {
    GQ_TAIL(i);
    GQ_TAIL(i + 4);
  }
  acc.x += __shfl_xor(acc.x, 16); acc.x += __shfl_xor(acc.x, 32);
  acc.y += __shfl_xor(acc.y, 16); acc.y += __shfl_xor(acc.y, 32);
  acc.z += __shfl_xor(acc.z, 16); acc.z += __shfl_xor(acc.z, 32);
  acc.w += __shfl_xor(acc.w, 16); acc.w += __shfl_xor(acc.w, 32);
  if (sub == 0) {
    int o = pk_fp8x4(fmaxf(acc.x, 0.f), fmaxf(acc.y, 0.f),
                     fmaxf(acc.z, 0.f), fmaxf(acc.w, 0.f));
    *(int*)(y + ((size_t)r << 6) + 4 * fl) = o;   // fused ReLU, fp8 store
  }
}

// ---------------- Linear2 via MFMA: A = fp8 from global -> bf16 frags --------
__global__ __launch_bounds__(256) void lin2_kernel(
    const unsigned char* __restrict__ yin, const float* __restrict__ W2,
    const float* __restrict__ b2, unsigned char* __restrict__ xout, int n) {
  __shared__ short sB[64 * BSTR];
  const int t = threadIdx.x;
  const int base = blockIdx.x * 64;
  for (int idx = t; idx < 64 * 64; idx += 256) {
    int k = idx >> 6, nn = idx & 63;
    sB[nn * BSTR + k] = f2bfs(W2[k * HID + nn]);
  }
  __syncthreads();

  const int lane = t & 63, w = t >> 6;
  const int nl = lane & 15, q = lane >> 4;
  const unsigned char* xg = yin + (((size_t)(base + w * 16 + nl)) << 6) + q * 8;
  const short* pB = &sB[nl * BSTR + q * 8];
  fx4 ac0 = {0.f, 0.f, 0.f, 0.f}, ac1 = ac0, ac2 = ac0, ac3 = ac0;
#pragma unroll
  for (int kt = 0; kt < 2; ++kt) {
    uint2 u8 = *(const uint2*)(xg + kt * 32);
    fx2 f0 = __builtin_amdgcn_cvt_pk_f32_fp8(u8.x, false);
    fx2 f1 = __builtin_amdgcn_cvt_pk_f32_fp8(u8.x, true);
    fx2 f2 = __builtin_amdgcn_cvt_pk_f32_fp8(u8.y, false);
    fx2 f3 = __builtin_amdgcn_cvt_pk_f32_fp8(u8.y, true);
    bf16x8 a;
    a[0] = f2bfs(f0.x); a[1] = f2bfs(f0.y); a[2] = f2bfs(f1.x); a[3] = f2bfs(f1.y);
    a[4] = f2bfs(f2.x); a[5] = f2bfs(f2.y); a[6] = f2bfs(f3.x); a[7] = f2bfs(f3.y);
    bf16x8 b0  = *(const bf16x8*)(pB + kt * 32);
    bf16x8 b1v = *(const bf16x8*)(pB + 16 * BSTR + kt * 32);
    bf16x8 b2v = *(const bf16x8*)(pB + 32 * BSTR + kt * 32);
    bf16x8 b3v = *(const bf16x8*)(pB + 48 * BSTR + kt * 32);
    ac0 = __builtin_amdgcn_mfma_f32_16x16x32_bf16(a, b0,  ac0, 0, 0, 0);
    ac1 = __builtin_amdgcn_mfma_f32_16x16x32_bf16(a, b1v, ac1, 0, 0, 0);
    ac2 = __builtin_amdgcn_mfma_f32_16x16x32_bf16(a, b2v, ac2, 0, 0, 0);
    ac3 = __builtin_amdgcn_mfma_f32_16x16x32_bf16(a, b3v, ac3, 0, 0, 0);
  }
  const float bias0 = b2[nl], bias1 = b2[16 + nl],
              bias2 = b2[32 + nl], bias3 = b2[48 + nl];
#pragma unroll
  for (int r = 0; r < 4; ++r) {
    int node = base + w * 16 + q * 4 + r;
    if (node < n) {
      unsigned char* o = xout + ((size_t)node << 6);
      o[nl]      = f2fp8(ac0[r] + bias0);
      o[16 + nl] = f2fp8(ac1[r] + bias1);
      o[32 + nl] = f2fp8(ac2[r] + bias2);
      o[48 + nl] = f2fp8(ac3[r] + bias3);
    }
  }
}

// ---------------- SpMM2 (fp8 gather) + ReLU + Wout-dot -> block partial ------
__global__ __launch_bounds__(256) void spmm2_fused_kernel(
    const int* __restrict__ row_ptr, const int2* __restrict__ ce,
    const unsigned char* __restrict__ x, const float* __restrict__ Wout,
    float* __restrict__ partials, int n) {
  const int lane = threadIdx.x & 63;
  const int sub = lane >> 4;
  const int fl  = lane & 15;
  const int g = threadIdx.x >> 6;
  const int r = blockIdx.x * 4 + g;
  const unsigned char* xp = x;
  const unsigned long long* cep = (const unsigned long long*)ce;
  float wpart = 0.f;
  if (r < n) {
    int i = row_ptr[r];
    const int end = row_ptr[r + 1];
    float4 acc = {0.f, 0.f, 0.f, 0.f};
    for (; i + 16 <= end; i += 16) {
      unsigned long long ea = __builtin_nontemporal_load(cep + i + sub);
      unsigned long long eb = __builtin_nontemporal_load(cep + i + 4 + sub);
      unsigned long long ec = __builtin_nontemporal_load(cep + i + 8 + sub);
      unsigned long long ed = __builtin_nontemporal_load(cep + i + 12 + sub);
      GQ(ea); GQ(eb); GQ(ec); GQ(ed);
    }
    for (; i < end; i += 8) {
      GQ_TAIL(i);
      GQ_TAIL(i + 4);
    }
    acc.x += __shfl_xor(acc.x, 16); acc.x += __shfl_xor(acc.x, 32);
    acc.y += __shfl_xor(acc.y, 16); acc.y += __shfl_xor(acc.y, 32);
    acc.z += __shfl_xor(acc.z, 16); acc.z += __shfl_xor(acc.z, 32);
    acc.w += __shfl_xor(acc.w, 16); acc.w += __shfl_xor(acc.w, 32);
    if (sub == 0) {
      const float4 wv = ((const float4*)Wout)[fl];
      wpart = fmaxf(acc.x, 0.f) * wv.x + fmaxf(acc.y, 0.f) * wv.y
            + fmaxf(acc.z, 0.f) * wv.z + fmaxf(acc.w, 0.f) * wv.w;
    }
  }
  for (int off = 32; off; off >>= 1) wpart += __shfl_down(wpart, off, 64);
  __shared__ float part[4];
  if (lane == 0) part[g] = wpart;
  __syncthreads();
  if (threadIdx.x == 0)
    partials[blockIdx.x] = part[0] + part[1] + part[2] + part[3];
}

// ---------------- final: sum 25k partials (1 block, float4) ------------------
__global__ __launch_bounds__(1024) void reduce_kernel(
    const float* __restrict__ partials, const float* __restrict__ bout,
    float* __restrict__ out, int m) {
  const int t = threadIdx.x;
  float s = 0.f;
  const int m4 = m >> 2;
  for (int i = t; i < m4; i += 1024) {
    float4 v = ((const float4*)partials)[i];
    s += v.x + v.y + v.z + v.w;
  }
  if (t < (m & 3)) s += partials[(m & ~3) + t];
  for (int off = 32; off; off >>= 1) s += __shfl_down(s, off, 64);
  __shared__ float wsum[16];
  if ((t & 63) == 0) wsum[t >> 6] = s;
  __syncthreads();
  if (t == 0) {
    float tot = bout[0];
    for (int w = 0; w < 16; ++w) tot += wsum[w];
    out[0] = tot;
  }
}

extern "C" void kernel_launch(void* const* d_in, const int* in_sizes, int n_in,
                              void* d_out, int out_size, void* d_ws, size_t ws_size,
                              hipStream_t stream) {
  const float* emb  = (const float*)d_in[0];
  const float* deg  = (const float*)d_in[1];
  const float* seed = (const float*)d_in[2];
  const int*   row  = (const int*)d_in[3];
  const int*   col  = (const int*)d_in[4];
  const float* vals = (const float*)d_in[5];
  const float* W1   = (const float*)d_in[6];
  const float* b1   = (const float*)d_in[7];
  const float* W2   = (const float*)d_in[8];
  const float* b2   = (const float*)d_in[9];
  const float* Wout = (const float*)d_in[10];
  const float* bout = (const float*)d_in[11];
  float* out = (float*)d_out;

  const int n  = in_sizes[0] / IN_EMB;   // 100000
  const int nE = in_sizes[3];            // 3200000
  const int nbkt = (n + ROWS_PER_BKT - 1) / ROWS_PER_BKT;   // 782

  const int lin_blocks  = (n + 63) / 64;
  const int row_blocks  = (n + 3) / 4;
  const int part_blocks = (nE + PART_CHUNK - 1) / PART_CHUNK;

  // ---- workspace layout ----
  char* ws = (char*)d_ws;
  int2* ce   = (int2*)ws;  ws += (size_t)nE * sizeof(int2);             // live to end
  char* tmpb = ws;
  int2* tmp  = (int2*)ws;  ws += (size_t)nE * sizeof(int2);             // dead after sort
  unsigned char* xa = (unsigned char*)ws;  ws += ((size_t)n * HID + 255) & ~255ULL;  // fp8
  unsigned char* xb = (unsigned char*)ws;  ws += ((size_t)n * HID + 255) & ~255ULL;  // fp8
  int* row_ptr = (int*)ws; ws += ((size_t)(n + 1) * 4 + 255) & ~255ULL;
  int* bcnt    = (int*)ws; ws += ((size_t)nbkt * 4 + 255) & ~255ULL;
  int* bstart  = (int*)ws; ws += ((size_t)(nbkt + 1) * 4 + 255) & ~255ULL;
  int* bcur    = (int*)ws; ws += ((size_t)nbkt * 4 + 255) & ~255ULL;
  float* partials = (float*)ws;                                         // row_blocks floats
  unsigned char* ya = (unsigned char*)tmpb;   // alias: tmp dead before spmm1 writes ya

  // ---- CSR build ----
  hipMemsetAsync(bcnt, 0, (size_t)nbkt * sizeof(int), stream);
  bhist_kernel<<<1024, 256, 0, stream>>>(row, bcnt, nE, nbkt);
  bscan_kernel<<<1, 1024, 0, stream>>>(bcnt, bstart, bcur, row_ptr, n, nbkt);
  partition_kernel<<<part_blocks, 512, 0, stream>>>(row, col, vals, bcur, tmp, nE);
  bucket_sort_kernel<<<nbkt, 512, 0, stream>>>(bstart, tmp, ce, row_ptr, n);

  // ---- network ----
  lin1_kernel<<<lin_blocks, 256, 0, stream>>>(emb, deg, seed, W1, b1, xa, n);
  spmm_csr_kernel<<<row_blocks, 256, 0, stream>>>(row_ptr, ce, xa, ya, n);
  lin2_kernel<<<lin_blocks, 256, 0, stream>>>(ya, W2, b2, xb, n);
  spmm2_fused_kernel<<<row_blocks, 256, 0, stream>>>(row_ptr, ce, xb, Wout, partials, n);
  reduce_kernel<<<1, 1024, 0, stream>>>(partials, bout, out, row_blocks);
}